// Round 2
// baseline (236.890 us; speedup 1.0000x reference)
//
#include <hip/hip_runtime.h>
#include <hip/hip_fp16.h>
#include <math.h>

#define Bb 2
#define Hh 8
#define Tt 4096
#define Kk 128
#define Vv 128
#define Ss 128
#define Cc 32
#define BH (Bb*Hh)
#define SCALE 0.08838834764831845f  /* 1/sqrt(128) */

// ---- workspace layout (in floats) ----
#define OFF_LFACC  0
#define OFF_FGEXP  (OFF_LFACC + BH*Tt)            // 65536
#define OFF_LFLAST (OFF_FGEXP + BH*Tt)            // 131072
#define OFF_MINTRA (OFF_LFLAST + BH*Cc)           // 131584
#define OFF_MPREV  (OFF_MINTRA + BH*Cc)           // 132096
#define OFF_E1     (OFF_MPREV + BH*Cc)            // 132608
#define OFF_E2     (OFF_E1 + BH*Cc)               // 133120
#define OFF_KV     (OFF_E2 + BH*Cc)               // 133632  (becomes c_prev)
#define OFF_KSUM   (OFF_KV + (size_t)BH*Cc*Kk*Vv) // 8522240 (becomes n_prev)
// total = 8587776 floats = ~34.4 MB

// ---------------------------------------------------------------------------
// Kernel 1: per-chunk gates: lf = logsigmoid(f), lfacc = cumsum, lflast,
// m_intra, fgexp = exp(i + lflast - lfacc - m_intra)
// grid = BH*Cc blocks, 128 threads
// ---------------------------------------------------------------------------
__global__ __launch_bounds__(128) void k_gates(const float* __restrict__ ig,
                                               const float* __restrict__ fg,
                                               float* __restrict__ ws) {
    int blk = blockIdx.x;
    int bh = blk >> 5;        // /Cc
    int c  = blk & 31;
    int t  = threadIdx.x;
    int gidx = bh * Tt + c * Ss + t;

    float x  = fg[gidx];
    float lf = fminf(x, 0.f) - log1pf(expf(-fabsf(x)));   // stable logsigmoid

    __shared__ float sbuf[Ss];
    __shared__ float red[Ss];
    sbuf[t] = lf;
    __syncthreads();
    // inclusive prefix sum (Hillis-Steele)
    for (int off = 1; off < Ss; off <<= 1) {
        float vv_ = (t >= off) ? sbuf[t - off] : 0.f;
        __syncthreads();
        sbuf[t] += vv_;
        __syncthreads();
    }
    float lfacc  = sbuf[t];
    float lflast = sbuf[Ss - 1];
    float iv  = ig[gidx];
    float fwd = iv + lflast - lfacc;

    red[t] = fwd;
    __syncthreads();
    for (int off = Ss / 2; off > 0; off >>= 1) {
        if (t < off) red[t] = fmaxf(red[t], red[t + off]);
        __syncthreads();
    }
    float mi = red[0];

    ws[OFF_LFACC + gidx] = lfacc;
    ws[OFF_FGEXP + gidx] = expf(fwd - mi);
    if (t == 0) {
        ws[OFF_LFLAST + blk] = lflast;
        ws[OFF_MINTRA + blk] = mi;
    }
}

// ---------------------------------------------------------------------------
// Kernel 2: per-chunk kv[k][v] = sum_t k[t,k]*v[t,v]*fgexp[t], ksum[k].
// 256 threads = 16x16 tiles of 8x8. grid = BH*Cc.
// ---------------------------------------------------------------------------
__global__ __launch_bounds__(256) void k_kv(const float* __restrict__ kg,
                                            const float* __restrict__ vg,
                                            float* __restrict__ ws) {
    int blk = blockIdx.x;
    int bh = blk >> 5;
    int c  = blk & 31;
    int tid = threadIdx.x;

    const float* kb = kg + ((size_t)bh * Tt + (size_t)c * Ss) * Kk;
    const float* vb = vg + ((size_t)bh * Tt + (size_t)c * Ss) * Vv;

    __shared__ float sfg[Ss];
    if (tid < Ss) sfg[tid] = ws[OFF_FGEXP + bh * Tt + c * Ss + tid];
    __syncthreads();

    int kkx = (tid >> 4) * 8;
    int vvx = (tid & 15) * 8;

    float acc[8][8];
    float ksm[8];
#pragma unroll
    for (int a = 0; a < 8; a++) {
        ksm[a] = 0.f;
#pragma unroll
        for (int b = 0; b < 8; b++) acc[a][b] = 0.f;
    }

    for (int t = 0; t < Ss; t++) {
        float g = sfg[t];
        float4 ka0 = *(const float4*)&kb[t * Kk + kkx];
        float4 ka1 = *(const float4*)&kb[t * Kk + kkx + 4];
        float4 va0 = *(const float4*)&vb[t * Vv + vvx];
        float4 va1 = *(const float4*)&vb[t * Vv + vvx + 4];
        float kw[8] = {ka0.x * g, ka0.y * g, ka0.z * g, ka0.w * g,
                       ka1.x * g, ka1.y * g, ka1.z * g, ka1.w * g};
        float vw[8] = {va0.x, va0.y, va0.z, va0.w, va1.x, va1.y, va1.z, va1.w};
#pragma unroll
        for (int a = 0; a < 8; a++) {
            ksm[a] += kw[a];
#pragma unroll
            for (int b = 0; b < 8; b++) acc[a][b] += kw[a] * vw[b];
        }
    }

    float* kvout = ws + OFF_KV + (size_t)blk * Kk * Vv;
#pragma unroll
    for (int a = 0; a < 8; a++) {
        float4 o0 = make_float4(acc[a][0], acc[a][1], acc[a][2], acc[a][3]);
        float4 o1 = make_float4(acc[a][4], acc[a][5], acc[a][6], acc[a][7]);
        *(float4*)&kvout[(size_t)(kkx + a) * Vv + vvx]     = o0;
        *(float4*)&kvout[(size_t)(kkx + a) * Vv + vvx + 4] = o1;
    }
    if ((tid & 15) == 0) {
        float* kso = ws + OFF_KSUM + (size_t)blk * Kk;
#pragma unroll
        for (int a = 0; a < 8; a++) kso[kkx + a] = ksm[a];
    }
}

// ---------------------------------------------------------------------------
// Kernel 3a: per-head scan coefficients.
// CRITICAL reference quirk: jax step() returns (c, n, m) with m NEVER updated
// to m_new — the carry max stays m0 for ALL chunks, and m_prev == m0
// everywhere. Replicate exactly.
// ---------------------------------------------------------------------------
__global__ void k_scan_coef(const float* __restrict__ m0, float* __restrict__ ws) {
    int bh = threadIdx.x;
    if (bh >= BH) return;
    const float m = m0[bh];                  // fixed for all chunks (ref quirk)
    for (int c = 0; c < Cc; c++) {
        int blk = bh * Cc + c;
        float lfl = ws[OFF_LFLAST + blk];
        float mi  = ws[OFF_MINTRA + blk];
        float mn  = fmaxf(lfl + m, mi);
        ws[OFF_MPREV + blk] = m;             // state BEFORE this chunk == m0
        ws[OFF_E1 + blk] = expf(lfl + m - mn);
        ws[OFF_E2 + blk] = expf(mi - mn);
        // NOTE: no `m = mn` — reference never rebinds the carry max.
    }
}

// ---------------------------------------------------------------------------
// Kernel 3b: parallel elementwise application of the chunk scan.
// In-place: kv buffer -> c_prev (state before chunk), ksum -> n_prev.
// grid = BH*K*V/256 + BH*K/256 = 1032 blocks.
// ---------------------------------------------------------------------------
__global__ __launch_bounds__(256) void k_scan_apply(const float* __restrict__ C0,
                                                    const float* __restrict__ n0,
                                                    float* __restrict__ ws) {
    const int NC = BH * Kk * Vv;       // 262144
    int gid = blockIdx.x * 256 + threadIdx.x;
    if (gid < NC) {
        int bh  = gid / (Kk * Vv);
        int idx = gid % (Kk * Vv);
        float st = C0[gid];
        float* base = ws + OFF_KV + (size_t)bh * Cc * Kk * Vv + idx;
        const float* e1p = ws + OFF_E1 + bh * Cc;
        const float* e2p = ws + OFF_E2 + bh * Cc;
        for (int c = 0; c < Cc; c++) {
            float* p = base + (size_t)c * Kk * Vv;
            float kvv = *p;
            *p = st;                              // c_prev for chunk c
            st = st * e1p[c] + kvv * e2p[c];
        }
    } else {
        int g2 = gid - NC;                        // 0..BH*Kk-1
        int bh = g2 / Kk;
        float st = n0[g2];
        float* base = ws + OFF_KSUM + (size_t)bh * Cc * Kk + (g2 % Kk);
        const float* e1p = ws + OFF_E1 + bh * Cc;
        const float* e2p = ws + OFF_E2 + bh * Cc;
        for (int c = 0; c < Cc; c++) {
            float* p = base + (size_t)c * Kk;
            float kvv = *p;
            *p = st;                              // n_prev for chunk c
            st = st * e1p[c] + kvv * e2p[c];
        }
    }
}

// ---------------------------------------------------------------------------
// Kernel 4: intra-chunk scores + normalization + output.
// 256 threads. LDS: M^T as fp16 [t][s] (32KB) + fp32 rowsum tree (8KB) + small.
// grid = BH*Cc.
// ---------------------------------------------------------------------------
__global__ __launch_bounds__(256) void k_out(const float* __restrict__ qg,
                                             const float* __restrict__ kg,
                                             const float* __restrict__ vg,
                                             const float* __restrict__ ig,
                                             float* __restrict__ ws,
                                             float* __restrict__ out) {
    int blk = blockIdx.x;
    int bh = blk >> 5;
    int c  = blk & 31;
    int tid = threadIdx.x;

    __shared__ __half Mt[Ss * Ss];     // scores, transposed: Mt[t*128 + s]
    __shared__ float sred[16 * Ss];    // row-sum partials per t-group
    __shared__ float sbt[Ss];          // b_t = i[t] - lfacc[t]
    __shared__ float sas[Ss];          // a_s = lfacc[s] - Gstab[s] = -max(gpre, m_prev)
    __shared__ float siw[Ss];          // scale * inter_w[s]
    __shared__ float smn[Ss];          // M_norm[s]
    __shared__ float sscan[Ss];        // prefix-max scratch

    const size_t rowbase = (size_t)bh * Tt + (size_t)c * Ss;
    const float* qrow = qg + rowbase * Kk;
    const float* krow = kg + rowbase * Kk;
    const float* vrow = vg + rowbase * Vv;
    float m_prev = ws[OFF_MPREV + blk];
    const float* nprev = ws + OFF_KSUM + (size_t)blk * Kk;
    const float* cprev = ws + OFF_KV + (size_t)blk * Kk * Vv;

    // ---- phase 0: stabilizers (threads 0..127, one per row) ----
    float engs = 0.f, intern = 0.f;
    bool p0 = tid < Ss;
    {
        float lfa = 0.f;
        if (p0) {
            lfa = ws[OFF_LFACC + bh * Tt + c * Ss + tid];
            float bt = ig[bh * Tt + c * Ss + tid] - lfa;
            sbt[tid] = bt;
            sscan[tid] = bt;
        }
        __syncthreads();
        for (int off = 1; off < Ss; off <<= 1) {
            float o = -3.4e38f;
            if (p0 && tid >= off) o = sscan[tid - off];
            __syncthreads();
            if (p0) sscan[tid] = fmaxf(sscan[tid], o);
            __syncthreads();
        }
        if (p0) {
            float gpre = sscan[tid];                    // cummax_{t<=s}(i-lfacc)
            float mx = fmaxf(gpre, m_prev);
            sas[tid] = -mx;                             // lfacc - Gstab
            float iw = SCALE * expf(m_prev - mx);       // scale folded into inter_w
            siw[tid] = iw;
            engs = expf(-(lfa + mx));                   // exp(-Gstab)
            // inter_n[s] = (q[s] . n_prev) * inter_w[s]   (q unscaled; scale in iw)
            float d = 0.f;
            for (int k0 = 0; k0 < Kk; k0 += 4) {
                float4 qv = *(const float4*)&qrow[(size_t)tid * Kk + k0];
                float4 nv = *(const float4*)&nprev[k0];
                d += qv.x * nv.x + qv.y * nv.y + qv.z * nv.z + qv.w * nv.w;
            }
            intern = d * iw;
        }
        __syncthreads();
    }

    // ---- phase 1: QK^T + gating, write M^T, fp32 row partial sums ----
    {
        int u  = tid & 15;        // s = u + 16*m (interleaved rows)
        int tg = tid >> 4;        // t-tile
        int tt = tg * 8;
        float acc[8][8];
#pragma unroll
        for (int a = 0; a < 8; a++)
#pragma unroll
            for (int b = 0; b < 8; b++) acc[a][b] = 0.f;

        for (int k0 = 0; k0 < Kk; k0 += 4) {
            float4 qv[8], kv4[8];
#pragma unroll
            for (int m = 0; m < 8; m++)
                qv[m] = *(const float4*)&qrow[(size_t)(u + 16 * m) * Kk + k0];
#pragma unroll
            for (int j = 0; j < 8; j++)
                kv4[j] = *(const float4*)&krow[(size_t)(tt + j) * Kk + k0];
#pragma unroll
            for (int m = 0; m < 8; m++)
#pragma unroll
                for (int j = 0; j < 8; j++)
                    acc[m][j] += qv[m].x * kv4[j].x + qv[m].y * kv4[j].y +
                                 qv[m].z * kv4[j].z + qv[m].w * kv4[j].w;
        }

        float asv[8], btv[8], rp[8];
#pragma unroll
        for (int m = 0; m < 8; m++) { asv[m] = sas[u + 16 * m]; rp[m] = 0.f; }
#pragma unroll
        for (int j = 0; j < 8; j++) btv[j] = sbt[tt + j];

#pragma unroll
        for (int m = 0; m < 8; m++) {
            int s = u + 16 * m;
#pragma unroll
            for (int j = 0; j < 8; j++) {
                int t = tt + j;
                float val = 0.f;
                if (t <= s) {
                    val = acc[m][j] * SCALE * expf(asv[m] + btv[j]);
                    rp[m] += val;
                }
                Mt[t * Ss + s] = __float2half(val);
            }
        }
#pragma unroll
        for (int m = 0; m < 8; m++) sred[tg * Ss + u + 16 * m] = rp[m];
    }
    __syncthreads();

    // ---- phase 1.5: M_norm ----
    if (p0) {
        float rs = 0.f;
#pragma unroll
        for (int g = 0; g < 16; g++) rs += sred[g * Ss + tid];
        smn[tid] = fmaxf(fabsf(rs + intern), engs);
    }
    __syncthreads();

    // ---- phase 2: h = (M^T . v  +  inter_w * (q . c_prev)) / M_norm ----
    {
        int w   = tid >> 4;          // s = w + 16*m
        int vvx = (tid & 15) * 8;
        float acc2[8][8];
#pragma unroll
        for (int a = 0; a < 8; a++)
#pragma unroll
            for (int b = 0; b < 8; b++) acc2[a][b] = 0.f;

        // PV: sum_t M[s,t] * v[t,:]
        for (int t = 0; t < Ss; t++) {
            float4 v0 = *(const float4*)&vrow[(size_t)t * Vv + vvx];
            float4 v1 = *(const float4*)&vrow[(size_t)t * Vv + vvx + 4];
#pragma unroll
            for (int m = 0; m < 8; m++) {
                float mv = __half2float(Mt[t * Ss + w + 16 * m]);
                acc2[m][0] += mv * v0.x;  acc2[m][1] += mv * v0.y;
                acc2[m][2] += mv * v0.z;  acc2[m][3] += mv * v0.w;
                acc2[m][4] += mv * v1.x;  acc2[m][5] += mv * v1.y;
                acc2[m][6] += mv * v1.z;  acc2[m][7] += mv * v1.w;
            }
        }

        // inter: inter_w[s] * sum_k q[s,k] * c_prev[k,:]
        float iw2[8];
#pragma unroll
        for (int m = 0; m < 8; m++) iw2[m] = siw[w + 16 * m];

        for (int k0 = 0; k0 < Kk; k0 += 4) {
            float4 qv[8];
#pragma unroll
            for (int m = 0; m < 8; m++)
                qv[m] = *(const float4*)&qrow[(size_t)(w + 16 * m) * Kk + k0];
#pragma unroll
            for (int kk = 0; kk < 4; kk++) {
                float4 cv0 = *(const float4*)&cprev[(size_t)(k0 + kk) * Vv + vvx];
                float4 cv1 = *(const float4*)&cprev[(size_t)(k0 + kk) * Vv + vvx + 4];
#pragma unroll
                for (int m = 0; m < 8; m++) {
                    float qk = (kk == 0 ? qv[m].x : kk == 1 ? qv[m].y :
                                kk == 2 ? qv[m].z : qv[m].w);
                    float qs = qk * iw2[m];
                    acc2[m][0] += qs * cv0.x;  acc2[m][1] += qs * cv0.y;
                    acc2[m][2] += qs * cv0.z;  acc2[m][3] += qs * cv0.w;
                    acc2[m][4] += qs * cv1.x;  acc2[m][5] += qs * cv1.y;
                    acc2[m][6] += qs * cv1.z;  acc2[m][7] += qs * cv1.w;
                }
            }
        }

        float* orow = out + rowbase * Vv;
#pragma unroll
        for (int m = 0; m < 8; m++) {
            int s = w + 16 * m;
            float rn = 1.0f / smn[s];
            float4 o0 = make_float4(acc2[m][0] * rn, acc2[m][1] * rn,
                                    acc2[m][2] * rn, acc2[m][3] * rn);
            float4 o1 = make_float4(acc2[m][4] * rn, acc2[m][5] * rn,
                                    acc2[m][6] * rn, acc2[m][7] * rn);
            *(float4*)&orow[(size_t)s * Vv + vvx]     = o0;
            *(float4*)&orow[(size_t)s * Vv + vvx + 4] = o1;
        }
    }
}

// ---------------------------------------------------------------------------
extern "C" void kernel_launch(void* const* d_in, const int* in_sizes, int n_in,
                              void* d_out, int out_size, void* d_ws, size_t ws_size,
                              hipStream_t stream) {
    (void)in_sizes; (void)n_in; (void)out_size; (void)ws_size;
    const float* q  = (const float*)d_in[0];
    const float* k  = (const float*)d_in[1];
    const float* v  = (const float*)d_in[2];
    const float* ig = (const float*)d_in[3];
    const float* fg = (const float*)d_in[4];
    const float* C0 = (const float*)d_in[5];
    const float* n0 = (const float*)d_in[6];
    const float* m0 = (const float*)d_in[7];
    float* out = (float*)d_out;
    float* ws  = (float*)d_ws;

    k_gates<<<BH * Cc, Ss, 0, stream>>>(ig, fg, ws);
    k_kv<<<BH * Cc, 256, 0, stream>>>(k, v, ws);
    k_scan_coef<<<1, 64, 0, stream>>>(m0, ws);
    k_scan_apply<<<(BH * Kk * Vv) / 256 + (BH * Kk) / 256, 256, 0, stream>>>(C0, n0, ws);
    k_out<<<BH * Cc, 256, 0, stream>>>(q, k, v, ig, ws, out);
}

// Round 4
// 101.249 us; speedup vs baseline: 2.3397x; 2.3397x over previous
//
#include <hip/hip_runtime.h>
#include <hip/hip_fp16.h>
#include <math.h>

#define Bb 2
#define Hh 8
#define Tt 4096
#define Kk 128
#define Vv 128
#define Ss 128
#define Cc 32
#define BH (Bb*Hh)
#define SCALE 0.08838834764831845f  /* 1/sqrt(128) */

// ---- workspace layout (in floats) ----
#define OFF_LFACC  0
#define OFF_FGEXP  (OFF_LFACC + BH*Tt)            // 65536
#define OFF_LFLAST (OFF_FGEXP + BH*Tt)            // 131072
#define OFF_MINTRA (OFF_LFLAST + BH*Cc)           // 131584
#define OFF_MPREV  (OFF_MINTRA + BH*Cc)           // 132096
#define OFF_E1     (OFF_MPREV + BH*Cc)            // 132608
#define OFF_E2     (OFF_E1 + BH*Cc)               // 133120
#define OFF_KV     (OFF_E2 + BH*Cc)               // 133632  (becomes c_prev)
#define OFF_KSUM   (OFF_KV + (size_t)BH*Cc*Kk*Vv) // 8522240 (becomes n_prev)

typedef _Float16 f16x8 __attribute__((ext_vector_type(8)));
typedef _Float16 f16x4 __attribute__((ext_vector_type(4)));
typedef float f32x4 __attribute__((ext_vector_type(4)));

// ---------------------------------------------------------------------------
// Kernel 1: per-chunk gates (unchanged)
// ---------------------------------------------------------------------------
__global__ __launch_bounds__(128) void k_gates(const float* __restrict__ ig,
                                               const float* __restrict__ fg,
                                               float* __restrict__ ws) {
    int blk = blockIdx.x;
    int bh = blk >> 5;
    int c  = blk & 31;
    int t  = threadIdx.x;
    int gidx = bh * Tt + c * Ss + t;

    float x  = fg[gidx];
    float lf = fminf(x, 0.f) - log1pf(expf(-fabsf(x)));

    __shared__ float sbuf[Ss];
    __shared__ float red[Ss];
    sbuf[t] = lf;
    __syncthreads();
    for (int off = 1; off < Ss; off <<= 1) {
        float vv_ = (t >= off) ? sbuf[t - off] : 0.f;
        __syncthreads();
        sbuf[t] += vv_;
        __syncthreads();
    }
    float lfacc  = sbuf[t];
    float lflast = sbuf[Ss - 1];
    float iv  = ig[gidx];
    float fwd = iv + lflast - lfacc;

    red[t] = fwd;
    __syncthreads();
    for (int off = Ss / 2; off > 0; off >>= 1) {
        if (t < off) red[t] = fmaxf(red[t], red[t + off]);
        __syncthreads();
    }
    float mi = red[0];

    ws[OFF_LFACC + gidx] = lfacc;
    ws[OFF_FGEXP + gidx] = expf(fwd - mi);
    if (t == 0) {
        ws[OFF_LFLAST + blk] = lflast;
        ws[OFF_MINTRA + blk] = mi;
    }
}

// ---------------------------------------------------------------------------
// Kernel 2: per-chunk kv + ksum (unchanged fp32 version)
// ---------------------------------------------------------------------------
__global__ __launch_bounds__(256) void k_kv(const float* __restrict__ kg,
                                            const float* __restrict__ vg,
                                            float* __restrict__ ws) {
    int blk = blockIdx.x;
    int bh = blk >> 5;
    int c  = blk & 31;
    int tid = threadIdx.x;

    const float* kb = kg + ((size_t)bh * Tt + (size_t)c * Ss) * Kk;
    const float* vb = vg + ((size_t)bh * Tt + (size_t)c * Ss) * Vv;

    __shared__ float sfg[Ss];
    if (tid < Ss) sfg[tid] = ws[OFF_FGEXP + bh * Tt + c * Ss + tid];
    __syncthreads();

    int kkx = (tid >> 4) * 8;
    int vvx = (tid & 15) * 8;

    float acc[8][8];
    float ksm[8];
#pragma unroll
    for (int a = 0; a < 8; a++) {
        ksm[a] = 0.f;
#pragma unroll
        for (int b = 0; b < 8; b++) acc[a][b] = 0.f;
    }

    for (int t = 0; t < Ss; t++) {
        float g = sfg[t];
        float4 ka0 = *(const float4*)&kb[t * Kk + kkx];
        float4 ka1 = *(const float4*)&kb[t * Kk + kkx + 4];
        float4 va0 = *(const float4*)&vb[t * Vv + vvx];
        float4 va1 = *(const float4*)&vb[t * Vv + vvx + 4];
        float kw[8] = {ka0.x * g, ka0.y * g, ka0.z * g, ka0.w * g,
                       ka1.x * g, ka1.y * g, ka1.z * g, ka1.w * g};
        float vw[8] = {va0.x, va0.y, va0.z, va0.w, va1.x, va1.y, va1.z, va1.w};
#pragma unroll
        for (int a = 0; a < 8; a++) {
            ksm[a] += kw[a];
#pragma unroll
            for (int b = 0; b < 8; b++) acc[a][b] += kw[a] * vw[b];
        }
    }

    float* kvout = ws + OFF_KV + (size_t)blk * Kk * Vv;
#pragma unroll
    for (int a = 0; a < 8; a++) {
        float4 o0 = make_float4(acc[a][0], acc[a][1], acc[a][2], acc[a][3]);
        float4 o1 = make_float4(acc[a][4], acc[a][5], acc[a][6], acc[a][7]);
        *(float4*)&kvout[(size_t)(kkx + a) * Vv + vvx]     = o0;
        *(float4*)&kvout[(size_t)(kkx + a) * Vv + vvx + 4] = o1;
    }
    if ((tid & 15) == 0) {
        float* kso = ws + OFF_KSUM + (size_t)blk * Kk;
#pragma unroll
        for (int a = 0; a < 8; a++) kso[kkx + a] = ksm[a];
    }
}

// ---------------------------------------------------------------------------
// Kernel 3a: scan coefficients. Reference quirk: carry max m is NEVER
// updated — m_prev == m0 for all chunks. Replicate exactly.
// ---------------------------------------------------------------------------
__global__ void k_scan_coef(const float* __restrict__ m0, float* __restrict__ ws) {
    int bh = threadIdx.x;
    if (bh >= BH) return;
    const float m = m0[bh];
    for (int c = 0; c < Cc; c++) {
        int blk = bh * Cc + c;
        float lfl = ws[OFF_LFLAST + blk];
        float mi  = ws[OFF_MINTRA + blk];
        float mn  = fmaxf(lfl + m, mi);
        ws[OFF_MPREV + blk] = m;
        ws[OFF_E1 + blk] = expf(lfl + m - mn);
        ws[OFF_E2 + blk] = expf(mi - mn);
    }
}

// ---------------------------------------------------------------------------
// Kernel 3b: scan application (unchanged)
// ---------------------------------------------------------------------------
__global__ __launch_bounds__(256) void k_scan_apply(const float* __restrict__ C0,
                                                    const float* __restrict__ n0,
                                                    float* __restrict__ ws) {
    const int NC = BH * Kk * Vv;
    int gid = blockIdx.x * 256 + threadIdx.x;
    if (gid < NC) {
        int bh  = gid / (Kk * Vv);
        int idx = gid % (Kk * Vv);
        float st = C0[gid];
        float* base = ws + OFF_KV + (size_t)bh * Cc * Kk * Vv + idx;
        const float* e1p = ws + OFF_E1 + bh * Cc;
        const float* e2p = ws + OFF_E2 + bh * Cc;
        for (int c = 0; c < Cc; c++) {
            float* p = base + (size_t)c * Kk * Vv;
            float kvv = *p;
            *p = st;
            st = st * e1p[c] + kvv * e2p[c];
        }
    } else {
        int g2 = gid - NC;
        int bh = g2 / Kk;
        float st = n0[g2];
        float* base = ws + OFF_KSUM + (size_t)bh * Cc * Kk + (g2 % Kk);
        const float* e1p = ws + OFF_E1 + bh * Cc;
        const float* e2p = ws + OFF_E2 + bh * Cc;
        for (int c = 0; c < Cc; c++) {
            float* p = base + (size_t)c * Kk;
            float kvv = *p;
            *p = st;
            st = st * e1p[c] + kvv * e2p[c];
        }
    }
}

// ---------------------------------------------------------------------------
// Kernel 4: MFMA intra-chunk scores + output — FP16 variant.
// Round-3 bf16 version validated structurally (error = bf16 eps scale);
// fp16 (2^-11) cuts quantization error 4x at identical speed/layout.
// mfma_f32_16x16x32_f16 fragment maps (same geometry as bf16):
//   A: row = lane&15, k = 8*(lane>>4)+e ; B: col = lane&15, same k
//   D: col = lane&15, row = 4*(lane>>4)+reg
// LDS tiles swizzled: element col ^= ((row&7)<<3)  (conflict-free b128)
// Xb (32KB) reused: K -> V^T -> c_prev^T. Mb (32KB) = gated M fp16.
// ---------------------------------------------------------------------------
__global__ __launch_bounds__(256, 2) void k_out_mfma(const float* __restrict__ qg,
                                                     const float* __restrict__ kg,
                                                     const float* __restrict__ vg,
                                                     const float* __restrict__ ig,
                                                     float* __restrict__ ws,
                                                     float* __restrict__ out) {
    __shared__ _Float16 Xb[Ss * Kk];    // staging: K, then V^T, then cprev^T
    __shared__ _Float16 Mb[Ss * Ss];    // gated scores, fp16, swizzled
    __shared__ float sbt[Ss], sas[Ss], siw[Ss], smn[Ss], srow[Ss];
    __shared__ float sintern[Ss], sengs[Ss], snp[Ss], sscan[Ss];

    int blk = blockIdx.x;
    int bh = blk >> 5;
    int c  = blk & 31;
    int tid = threadIdx.x;
    int lane = tid & 63;
    int w = tid >> 6;                   // wave id 0..3
    int l15 = lane & 15;
    int g = lane >> 4;                  // 0..3
    const int S0 = w * 32;
    const int swt = (l15 & 7) << 3;     // per-lane read swizzle (row&7 == l15&7)

    const size_t rowbase = (size_t)bh * Tt + (size_t)c * Ss;
    const float* qp = qg + rowbase * Kk;
    const float* kp = kg + rowbase * Kk;
    const float* vp = vg + rowbase * Vv;
    const float* nprev = ws + OFF_KSUM + (size_t)blk * Kk;
    const float* cprev = ws + OFF_KV + (size_t)blk * Kk * Vv;
    const float m_prev = ws[OFF_MPREV + blk];

    // ---- stage K into Xb (fp16, swizzled), row-major [t][k] ----
    {
        int t  = tid >> 1;
        int kh = (tid & 1) * 64;
        const float* src = kp + (size_t)t * Kk + kh;
        _Float16* dst = &Xb[t * Kk];
        int sw = (t & 7) << 3;
#pragma unroll
        for (int i = 0; i < 16; i++) {
            float4 f = *(const float4*)&src[4 * i];
            int col = (kh + 4 * i) ^ sw;
            f16x4 s4 = { (_Float16)f.x, (_Float16)f.y, (_Float16)f.z, (_Float16)f.w };
            *(f16x4*)&dst[col] = s4;
        }
    }

    // ---- load Q fragments (registers, reused for QK^T and inter) ----
    f16x8 qf[2][4];
#pragma unroll
    for (int si = 0; si < 2; si++) {
        int row = S0 + 16 * si + l15;
#pragma unroll
        for (int kk = 0; kk < 4; kk++) {
            const float* p = qp + (size_t)row * Kk + kk * 32 + g * 8;
            float4 a = *(const float4*)p;
            float4 b = *(const float4*)(p + 4);
            f16x8 r;
            r[0]=(_Float16)a.x; r[1]=(_Float16)a.y; r[2]=(_Float16)a.z; r[3]=(_Float16)a.w;
            r[4]=(_Float16)b.x; r[5]=(_Float16)b.y; r[6]=(_Float16)b.z; r[7]=(_Float16)b.w;
            qf[si][kk] = r;
        }
    }

    // ---- phase 0: stabilizers (threads 0..127) ----
    bool p0 = tid < Ss;
    float lfa = 0.f;
    if (p0) {
        lfa = ws[OFF_LFACC + bh * Tt + c * Ss + tid];
        float bt = ig[bh * Tt + c * Ss + tid] - lfa;
        sbt[tid] = bt;
        sscan[tid] = bt;
        snp[tid] = nprev[tid];
    }
    __syncthreads();
    for (int off = 1; off < Ss; off <<= 1) {
        float o = -3.4e38f;
        if (p0 && tid >= off) o = sscan[tid - off];
        __syncthreads();
        if (p0) sscan[tid] = fmaxf(sscan[tid], o);
        __syncthreads();
    }
    if (p0) {
        float mx = fmaxf(sscan[tid], m_prev);
        sas[tid] = -mx;
        siw[tid] = SCALE * __expf(m_prev - mx);
        sengs[tid] = __expf(-(lfa + mx));
    }
    __syncthreads();   // barrier0: Kb staged, phase0 arrays ready

    // ---- per-lane row constants ----
    float asr[2][4], siwr[2][4];
#pragma unroll
    for (int si = 0; si < 2; si++)
#pragma unroll
        for (int r = 0; r < 4; r++) {
            int sr = S0 + 16 * si + 4 * g + r;
            asr[si][r] = sas[sr];
            siwr[si][r] = siw[sr];
        }

    // ---- intern[s] = (q . n_prev) * iw, via q fragments ----
#pragma unroll
    for (int si = 0; si < 2; si++) {
        float d = 0.f;
#pragma unroll
        for (int kk = 0; kk < 4; kk++)
#pragma unroll
            for (int e = 0; e < 8; e++)
                d += (float)qf[si][kk][e] * snp[kk * 32 + g * 8 + e];
        d += __shfl_xor(d, 16);
        d += __shfl_xor(d, 32);
        if (g == 0) {
            int s = S0 + 16 * si + l15;
            sintern[s] = d * siw[s];
        }
    }

    // ---- QK^T + gating -> Mb (fp16) + row sums ----
    float rp[2][4];
#pragma unroll
    for (int si = 0; si < 2; si++)
#pragma unroll
        for (int r = 0; r < 4; r++) rp[si][r] = 0.f;

    for (int tj = 0; tj <= 2 * w + 1; tj++) {
        int trow = tj * 16 + l15;
        f16x8 bfr[4];
#pragma unroll
        for (int kk = 0; kk < 4; kk++)
            bfr[kk] = *(const f16x8*)&Xb[trow * Kk + ((kk * 32 + g * 8) ^ swt)];
        float btv = sbt[trow];
#pragma unroll
        for (int si = 0; si < 2; si++) {
            if (tj > 2 * w + si) {
                // fully-masked tile (si==0, tj==2w+1): zero-fill Mb
#pragma unroll
                for (int r = 0; r < 4; r++) {
                    int sr = S0 + 4 * g + r;   // si==0 here
                    Mb[sr * Ss + (trow ^ ((sr & 7) << 3))] = (_Float16)0.f;
                }
                continue;
            }
            f32x4 acc = {0.f, 0.f, 0.f, 0.f};
#pragma unroll
            for (int kk = 0; kk < 4; kk++)
                acc = __builtin_amdgcn_mfma_f32_16x16x32_f16(qf[si][kk], bfr[kk], acc, 0, 0, 0);
#pragma unroll
            for (int r = 0; r < 4; r++) {
                int sr = S0 + 16 * si + 4 * g + r;
                float val = 0.f;
                if (trow <= sr) {
                    val = acc[r] * SCALE * __expf(asr[si][r] + btv);
                    rp[si][r] += val;
                }
                Mb[sr * Ss + (trow ^ ((sr & 7) << 3))] = (_Float16)val;
            }
        }
    }

    // ---- row-sum reduce across t-residues (lanes 0..15 of each group) ----
#pragma unroll
    for (int si = 0; si < 2; si++)
#pragma unroll
        for (int r = 0; r < 4; r++) {
            float t = rp[si][r];
            t += __shfl_xor(t, 1);
            t += __shfl_xor(t, 2);
            t += __shfl_xor(t, 4);
            t += __shfl_xor(t, 8);
            if (l15 == 0) srow[S0 + 16 * si + 4 * g + r] = t;
        }
    __syncthreads();   // barrier1: Mb + srow complete; Xb(K) free

    // ---- M_norm; stage V^T into Xb ----
    if (p0) smn[tid] = fmaxf(fabsf(srow[tid] + sintern[tid]), sengs[tid]);
    {
        int t  = tid >> 1;
        int vh = (tid & 1) * 64;
        const float* src = vp + (size_t)t * Vv + vh;
#pragma unroll
        for (int i = 0; i < 16; i++) {
            float4 f = *(const float4*)&src[4 * i];
            float vals[4] = { f.x, f.y, f.z, f.w };
#pragma unroll
            for (int j = 0; j < 4; j++) {
                int vv = vh + 4 * i + j;
                Xb[vv * Kk + (t ^ ((vv & 7) << 3))] = (_Float16)vals[j];
            }
        }
    }
    __syncthreads();   // barrier2: V^T staged, smn ready

    // ---- PV: hacc[s][v] += sum_t M[s,t] V[t,v] ----
    f32x4 hacc[2][8];
#pragma unroll
    for (int si = 0; si < 2; si++)
#pragma unroll
        for (int vj = 0; vj < 8; vj++) hacc[si][vj] = (f32x4){0.f, 0.f, 0.f, 0.f};

    for (int kkt = 0; kkt <= w; kkt++) {
        f16x8 af[2];
#pragma unroll
        for (int si = 0; si < 2; si++) {
            int sr = S0 + 16 * si + l15;
            af[si] = *(const f16x8*)&Mb[sr * Ss + ((kkt * 32 + g * 8) ^ swt)];
        }
#pragma unroll
        for (int vj = 0; vj < 8; vj++) {
            int vr = vj * 16 + l15;
            f16x8 bv = *(const f16x8*)&Xb[vr * Kk + ((kkt * 32 + g * 8) ^ swt)];
            hacc[0][vj] = __builtin_amdgcn_mfma_f32_16x16x32_f16(af[0], bv, hacc[0][vj], 0, 0, 0);
            hacc[1][vj] = __builtin_amdgcn_mfma_f32_16x16x32_f16(af[1], bv, hacc[1][vj], 0, 0, 0);
        }
    }
    __syncthreads();   // barrier3: done reading Xb(V^T)

    // ---- stage c_prev^T into Xb ----
    {
        int kr = tid >> 1;
        int vh = (tid & 1) * 64;
        const float* src = cprev + (size_t)kr * Vv + vh;
#pragma unroll
        for (int i = 0; i < 16; i++) {
            float4 f = *(const float4*)&src[4 * i];
            float vals[4] = { f.x, f.y, f.z, f.w };
#pragma unroll
            for (int j = 0; j < 4; j++) {
                int vv = vh + 4 * i + j;
                Xb[vv * Kk + (kr ^ ((vv & 7) << 3))] = (_Float16)vals[j];
            }
        }
    }
    __syncthreads();   // barrier4: c_prev^T staged

    // ---- inter: hacc += iw[s] * sum_k q[s,k] c_prev[k,v] ----
    for (int vj = 0; vj < 8; vj++) {
        int vr = vj * 16 + l15;
        f16x8 bcf[4];
#pragma unroll
        for (int kk = 0; kk < 4; kk++)
            bcf[kk] = *(const f16x8*)&Xb[vr * Kk + ((kk * 32 + g * 8) ^ swt)];
#pragma unroll
        for (int si = 0; si < 2; si++) {
            f32x4 tmp = {0.f, 0.f, 0.f, 0.f};
#pragma unroll
            for (int kk = 0; kk < 4; kk++)
                tmp = __builtin_amdgcn_mfma_f32_16x16x32_f16(qf[si][kk], bcf[kk], tmp, 0, 0, 0);
#pragma unroll
            for (int r = 0; r < 4; r++)
                hacc[si][vj][r] += tmp[r] * siwr[si][r];
        }
    }

    // ---- output: h = hacc / M_norm ----
    float rnv[2][4];
#pragma unroll
    for (int si = 0; si < 2; si++)
#pragma unroll
        for (int r = 0; r < 4; r++)
            rnv[si][r] = 1.0f / smn[S0 + 16 * si + 4 * g + r];

#pragma unroll
    for (int si = 0; si < 2; si++)
#pragma unroll
        for (int vj = 0; vj < 8; vj++)
#pragma unroll
            for (int r = 0; r < 4; r++) {
                int sr = S0 + 16 * si + 4 * g + r;
                out[(rowbase + sr) * Vv + vj * 16 + l15] = hacc[si][vj][r] * rnv[si][r];
            }
}

// ---------------------------------------------------------------------------
extern "C" void kernel_launch(void* const* d_in, const int* in_sizes, int n_in,
                              void* d_out, int out_size, void* d_ws, size_t ws_size,
                              hipStream_t stream) {
    (void)in_sizes; (void)n_in; (void)out_size; (void)ws_size;
    const float* q  = (const float*)d_in[0];
    const float* k  = (const float*)d_in[1];
    const float* v  = (const float*)d_in[2];
    const float* ig = (const float*)d_in[3];
    const float* fg = (const float*)d_in[4];
    const float* C0 = (const float*)d_in[5];
    const float* n0 = (const float*)d_in[6];
    const float* m0 = (const float*)d_in[7];
    float* out = (float*)d_out;
    float* ws  = (float*)d_ws;

    k_gates<<<BH * Cc, Ss, 0, stream>>>(ig, fg, ws);
    k_kv<<<BH * Cc, 256, 0, stream>>>(k, v, ws);
    k_scan_coef<<<1, 64, 0, stream>>>(m0, ws);
    k_scan_apply<<<(BH * Kk * Vv) / 256 + (BH * Kk) / 256, 256, 0, stream>>>(C0, n0, ws);
    k_out_mfma<<<BH * Cc, 256, 0, stream>>>(q, k, v, ig, ws, out);
}

// Round 5
// 82.756 us; speedup vs baseline: 2.8625x; 1.2235x over previous
//
#include <hip/hip_runtime.h>
#include <hip/hip_fp16.h>
#include <math.h>

#define Bb 2
#define Hh 8
#define Tt 4096
#define Kk 128
#define Vv 128
#define Ss 128
#define Cc 32
#define BH (Bb*Hh)
#define SCALE 0.08838834764831845f  /* 1/sqrt(128) */

// ---- workspace layout (in floats) ----
#define OFF_LFACC  0
#define OFF_FGEXP  (OFF_LFACC + BH*Tt)            // 65536
#define OFF_LFLAST (OFF_FGEXP + BH*Tt)            // 131072
#define OFF_MINTRA (OFF_LFLAST + BH*Cc)           // 131584
#define OFF_MPREV  (OFF_MINTRA + BH*Cc)           // 132096
#define OFF_E1     (OFF_MPREV + BH*Cc)            // 132608
#define OFF_E2     (OFF_E1 + BH*Cc)               // 133120
#define OFF_KV     (OFF_E2 + BH*Cc)               // 133632  (becomes c_prev)
#define OFF_KSUM   (OFF_KV + (size_t)BH*Cc*Kk*Vv) // 8522240 (becomes n_prev)

typedef _Float16 f16x8 __attribute__((ext_vector_type(8)));
typedef _Float16 f16x4 __attribute__((ext_vector_type(4)));
typedef float f32x4 __attribute__((ext_vector_type(4)));

// ---------------------------------------------------------------------------
// Kernel 1: per-chunk gates (unchanged)
// ---------------------------------------------------------------------------
__global__ __launch_bounds__(128) void k_gates(const float* __restrict__ ig,
                                               const float* __restrict__ fg,
                                               float* __restrict__ ws) {
    int blk = blockIdx.x;
    int bh = blk >> 5;
    int c  = blk & 31;
    int t  = threadIdx.x;
    int gidx = bh * Tt + c * Ss + t;

    float x  = fg[gidx];
    float lf = fminf(x, 0.f) - log1pf(expf(-fabsf(x)));

    __shared__ float sbuf[Ss];
    __shared__ float red[Ss];
    sbuf[t] = lf;
    __syncthreads();
    for (int off = 1; off < Ss; off <<= 1) {
        float vv_ = (t >= off) ? sbuf[t - off] : 0.f;
        __syncthreads();
        sbuf[t] += vv_;
        __syncthreads();
    }
    float lfacc  = sbuf[t];
    float lflast = sbuf[Ss - 1];
    float iv  = ig[gidx];
    float fwd = iv + lflast - lfacc;

    red[t] = fwd;
    __syncthreads();
    for (int off = Ss / 2; off > 0; off >>= 1) {
        if (t < off) red[t] = fmaxf(red[t], red[t + off]);
        __syncthreads();
    }
    float mi = red[0];

    ws[OFF_LFACC + gidx] = lfacc;
    ws[OFF_FGEXP + gidx] = expf(fwd - mi);
    if (t == 0) {
        ws[OFF_LFLAST + blk] = lflast;
        ws[OFF_MINTRA + blk] = mi;
    }
}

// ---------------------------------------------------------------------------
// Kernel 2 (NEW): MFMA kv + ksum.
// kv[kidx][vidx] = sum_t (k[t,kidx]*g[t]) * v[t,vidx]  — contraction over t.
// A = (g*K)^T staged [kidx][t] fp16; B = V^T staged [vidx][t] fp16; both with
// the XOR swizzle (col ^= (row&7)<<3) validated in k_out_mfma.
// ksum[kidx] = sum_t Kt[kidx][t] via per-row LDS reduction.
// 256 threads = 4 waves; wave w owns kidx in [32w, 32w+32).
// ---------------------------------------------------------------------------
__global__ __launch_bounds__(256, 2) void k_kv_mfma(const float* __restrict__ kg,
                                                    const float* __restrict__ vg,
                                                    float* __restrict__ ws) {
    __shared__ _Float16 Kt[Ss * Ss];   // (g*K)^T, swizzled
    __shared__ _Float16 Vt[Ss * Ss];   // V^T, swizzled
    __shared__ float sfg[Ss];

    int blk = blockIdx.x;
    int bh = blk >> 5;
    int c  = blk & 31;
    int tid = threadIdx.x;
    int lane = tid & 63;
    int w = tid >> 6;
    int l15 = lane & 15;
    int g = lane >> 4;
    const int S0 = w * 32;
    const int swt = (l15 & 7) << 3;

    const float* kb = kg + ((size_t)bh * Tt + (size_t)c * Ss) * Kk;
    const float* vb = vg + ((size_t)bh * Tt + (size_t)c * Ss) * Vv;

    if (tid < Ss) sfg[tid] = ws[OFF_FGEXP + bh * Tt + c * Ss + tid];
    __syncthreads();

    // ---- transpose-stage (g*K)^T and V^T ----
    {
        int t  = tid >> 1;
        int half = (tid & 1) * 64;
        float gt = sfg[t];
        const float* ksrc = kb + (size_t)t * Kk + half;
        const float* vsrc = vb + (size_t)t * Vv + half;
#pragma unroll
        for (int i = 0; i < 16; i++) {
            float4 kf = *(const float4*)&ksrc[4 * i];
            float4 vf = *(const float4*)&vsrc[4 * i];
            float kvals[4] = { kf.x, kf.y, kf.z, kf.w };
            float vvals[4] = { vf.x, vf.y, vf.z, vf.w };
#pragma unroll
            for (int j = 0; j < 4; j++) {
                int rr = half + 4 * i + j;           // kidx / vidx row
                int col = t ^ ((rr & 7) << 3);
                Kt[rr * Ss + col] = (_Float16)(kvals[j] * gt);
                Vt[rr * Ss + col] = (_Float16)vvals[j];
            }
        }
    }
    __syncthreads();

    // ---- ksum: per-row reduction of Kt (threads 0..127) ----
    if (tid < Ss) {
        int sw = (tid & 7) << 3;
        float s = 0.f;
#pragma unroll
        for (int i = 0; i < 16; i++) {
            f16x8 ld = *(const f16x8*)&Kt[tid * Ss + ((8 * i) ^ sw)];
#pragma unroll
            for (int e = 0; e < 8; e++) s += (float)ld[e];
        }
        ws[OFF_KSUM + (size_t)blk * Kk + tid] = s;
    }

    // ---- MFMA: kv = Kt · Vt^T (contraction over t) ----
    f16x8 af[2][4];
#pragma unroll
    for (int si = 0; si < 2; si++) {
        int kr = S0 + 16 * si + l15;
#pragma unroll
        for (int kk = 0; kk < 4; kk++)
            af[si][kk] = *(const f16x8*)&Kt[kr * Ss + ((kk * 32 + g * 8) ^ swt)];
    }

    f32x4 acc[2][8];
#pragma unroll
    for (int si = 0; si < 2; si++)
#pragma unroll
        for (int vj = 0; vj < 8; vj++) acc[si][vj] = (f32x4){0.f, 0.f, 0.f, 0.f};

#pragma unroll
    for (int vj = 0; vj < 8; vj++) {
        int vr = vj * 16 + l15;
#pragma unroll
        for (int kk = 0; kk < 4; kk++) {
            f16x8 bv = *(const f16x8*)&Vt[vr * Ss + ((kk * 32 + g * 8) ^ swt)];
            acc[0][vj] = __builtin_amdgcn_mfma_f32_16x16x32_f16(af[0][kk], bv, acc[0][vj], 0, 0, 0);
            acc[1][vj] = __builtin_amdgcn_mfma_f32_16x16x32_f16(af[1][kk], bv, acc[1][vj], 0, 0, 0);
        }
    }

    // ---- write kv (fp32, row-major [kidx][vidx]) ----
    float* kvout = ws + OFF_KV + (size_t)blk * Kk * Vv;
#pragma unroll
    for (int si = 0; si < 2; si++)
#pragma unroll
        for (int vj = 0; vj < 8; vj++)
#pragma unroll
            for (int r = 0; r < 4; r++) {
                int kr = S0 + 16 * si + 4 * g + r;
                kvout[(size_t)kr * Vv + vj * 16 + l15] = acc[si][vj][r];
            }
}

// ---------------------------------------------------------------------------
// Kernel 3a: scan coefficients. Reference quirk: carry max m is NEVER
// updated — m_prev == m0 for all chunks. Replicate exactly.
// ---------------------------------------------------------------------------
__global__ void k_scan_coef(const float* __restrict__ m0, float* __restrict__ ws) {
    int bh = threadIdx.x;
    if (bh >= BH) return;
    const float m = m0[bh];
    for (int c = 0; c < Cc; c++) {
        int blk = bh * Cc + c;
        float lfl = ws[OFF_LFLAST + blk];
        float mi  = ws[OFF_MINTRA + blk];
        float mn  = fmaxf(lfl + m, mi);
        ws[OFF_MPREV + blk] = m;
        ws[OFF_E1 + blk] = expf(lfl + m - mn);
        ws[OFF_E2 + blk] = expf(mi - mn);
    }
}

// ---------------------------------------------------------------------------
// Kernel 3b: scan application (unchanged)
// ---------------------------------------------------------------------------
__global__ __launch_bounds__(256) void k_scan_apply(const float* __restrict__ C0,
                                                    const float* __restrict__ n0,
                                                    float* __restrict__ ws) {
    const int NC = BH * Kk * Vv;
    int gid = blockIdx.x * 256 + threadIdx.x;
    if (gid < NC) {
        int bh  = gid / (Kk * Vv);
        int idx = gid % (Kk * Vv);
        float st = C0[gid];
        float* base = ws + OFF_KV + (size_t)bh * Cc * Kk * Vv + idx;
        const float* e1p = ws + OFF_E1 + bh * Cc;
        const float* e2p = ws + OFF_E2 + bh * Cc;
        for (int c = 0; c < Cc; c++) {
            float* p = base + (size_t)c * Kk * Vv;
            float kvv = *p;
            *p = st;
            st = st * e1p[c] + kvv * e2p[c];
        }
    } else {
        int g2 = gid - NC;
        int bh = g2 / Kk;
        float st = n0[g2];
        float* base = ws + OFF_KSUM + (size_t)bh * Cc * Kk + (g2 % Kk);
        const float* e1p = ws + OFF_E1 + bh * Cc;
        const float* e2p = ws + OFF_E2 + bh * Cc;
        for (int c = 0; c < Cc; c++) {
            float* p = base + (size_t)c * Kk;
            float kvv = *p;
            *p = st;
            st = st * e1p[c] + kvv * e2p[c];
        }
    }
}

// ---------------------------------------------------------------------------
// Kernel 4: MFMA intra-chunk scores + output — FP16 (unchanged from round 4)
// ---------------------------------------------------------------------------
__global__ __launch_bounds__(256, 2) void k_out_mfma(const float* __restrict__ qg,
                                                     const float* __restrict__ kg,
                                                     const float* __restrict__ vg,
                                                     const float* __restrict__ ig,
                                                     float* __restrict__ ws,
                                                     float* __restrict__ out) {
    __shared__ _Float16 Xb[Ss * Kk];    // staging: K, then V^T, then cprev^T
    __shared__ _Float16 Mb[Ss * Ss];    // gated scores, fp16, swizzled
    __shared__ float sbt[Ss], sas[Ss], siw[Ss], smn[Ss], srow[Ss];
    __shared__ float sintern[Ss], sengs[Ss], snp[Ss], sscan[Ss];

    int blk = blockIdx.x;
    int bh = blk >> 5;
    int c  = blk & 31;
    int tid = threadIdx.x;
    int lane = tid & 63;
    int w = tid >> 6;                   // wave id 0..3
    int l15 = lane & 15;
    int g = lane >> 4;                  // 0..3
    const int S0 = w * 32;
    const int swt = (l15 & 7) << 3;     // per-lane read swizzle (row&7 == l15&7)

    const size_t rowbase = (size_t)bh * Tt + (size_t)c * Ss;
    const float* qp = qg + rowbase * Kk;
    const float* kp = kg + rowbase * Kk;
    const float* vp = vg + rowbase * Vv;
    const float* nprev = ws + OFF_KSUM + (size_t)blk * Kk;
    const float* cprev = ws + OFF_KV + (size_t)blk * Kk * Vv;
    const float m_prev = ws[OFF_MPREV + blk];

    // ---- stage K into Xb (fp16, swizzled), row-major [t][k] ----
    {
        int t  = tid >> 1;
        int kh = (tid & 1) * 64;
        const float* src = kp + (size_t)t * Kk + kh;
        _Float16* dst = &Xb[t * Kk];
        int sw = (t & 7) << 3;
#pragma unroll
        for (int i = 0; i < 16; i++) {
            float4 f = *(const float4*)&src[4 * i];
            int col = (kh + 4 * i) ^ sw;
            f16x4 s4 = { (_Float16)f.x, (_Float16)f.y, (_Float16)f.z, (_Float16)f.w };
            *(f16x4*)&dst[col] = s4;
        }
    }

    // ---- load Q fragments (registers, reused for QK^T and inter) ----
    f16x8 qf[2][4];
#pragma unroll
    for (int si = 0; si < 2; si++) {
        int row = S0 + 16 * si + l15;
#pragma unroll
        for (int kk = 0; kk < 4; kk++) {
            const float* p = qp + (size_t)row * Kk + kk * 32 + g * 8;
            float4 a = *(const float4*)p;
            float4 b = *(const float4*)(p + 4);
            f16x8 r;
            r[0]=(_Float16)a.x; r[1]=(_Float16)a.y; r[2]=(_Float16)a.z; r[3]=(_Float16)a.w;
            r[4]=(_Float16)b.x; r[5]=(_Float16)b.y; r[6]=(_Float16)b.z; r[7]=(_Float16)b.w;
            qf[si][kk] = r;
        }
    }

    // ---- phase 0: stabilizers (threads 0..127) ----
    bool p0 = tid < Ss;
    float lfa = 0.f;
    if (p0) {
        lfa = ws[OFF_LFACC + bh * Tt + c * Ss + tid];
        float bt = ig[bh * Tt + c * Ss + tid] - lfa;
        sbt[tid] = bt;
        sscan[tid] = bt;
        snp[tid] = nprev[tid];
    }
    __syncthreads();
    for (int off = 1; off < Ss; off <<= 1) {
        float o = -3.4e38f;
        if (p0 && tid >= off) o = sscan[tid - off];
        __syncthreads();
        if (p0) sscan[tid] = fmaxf(sscan[tid], o);
        __syncthreads();
    }
    if (p0) {
        float mx = fmaxf(sscan[tid], m_prev);
        sas[tid] = -mx;
        siw[tid] = SCALE * __expf(m_prev - mx);
        sengs[tid] = __expf(-(lfa + mx));
    }
    __syncthreads();   // barrier0: Kb staged, phase0 arrays ready

    // ---- per-lane row constants ----
    float asr[2][4], siwr[2][4];
#pragma unroll
    for (int si = 0; si < 2; si++)
#pragma unroll
        for (int r = 0; r < 4; r++) {
            int sr = S0 + 16 * si + 4 * g + r;
            asr[si][r] = sas[sr];
            siwr[si][r] = siw[sr];
        }

    // ---- intern[s] = (q . n_prev) * iw, via q fragments ----
#pragma unroll
    for (int si = 0; si < 2; si++) {
        float d = 0.f;
#pragma unroll
        for (int kk = 0; kk < 4; kk++)
#pragma unroll
            for (int e = 0; e < 8; e++)
                d += (float)qf[si][kk][e] * snp[kk * 32 + g * 8 + e];
        d += __shfl_xor(d, 16);
        d += __shfl_xor(d, 32);
        if (g == 0) {
            int s = S0 + 16 * si + l15;
            sintern[s] = d * siw[s];
        }
    }

    // ---- QK^T + gating -> Mb (fp16) + row sums ----
    float rp[2][4];
#pragma unroll
    for (int si = 0; si < 2; si++)
#pragma unroll
        for (int r = 0; r < 4; r++) rp[si][r] = 0.f;

    for (int tj = 0; tj <= 2 * w + 1; tj++) {
        int trow = tj * 16 + l15;
        f16x8 bfr[4];
#pragma unroll
        for (int kk = 0; kk < 4; kk++)
            bfr[kk] = *(const f16x8*)&Xb[trow * Kk + ((kk * 32 + g * 8) ^ swt)];
        float btv = sbt[trow];
#pragma unroll
        for (int si = 0; si < 2; si++) {
            if (tj > 2 * w + si) {
                // fully-masked tile (si==0, tj==2w+1): zero-fill Mb
#pragma unroll
                for (int r = 0; r < 4; r++) {
                    int sr = S0 + 4 * g + r;   // si==0 here
                    Mb[sr * Ss + (trow ^ ((sr & 7) << 3))] = (_Float16)0.f;
                }
                continue;
            }
            f32x4 acc = {0.f, 0.f, 0.f, 0.f};
#pragma unroll
            for (int kk = 0; kk < 4; kk++)
                acc = __builtin_amdgcn_mfma_f32_16x16x32_f16(qf[si][kk], bfr[kk], acc, 0, 0, 0);
#pragma unroll
            for (int r = 0; r < 4; r++) {
                int sr = S0 + 16 * si + 4 * g + r;
                float val = 0.f;
                if (trow <= sr) {
                    val = acc[r] * SCALE * __expf(asr[si][r] + btv);
                    rp[si][r] += val;
                }
                Mb[sr * Ss + (trow ^ ((sr & 7) << 3))] = (_Float16)val;
            }
        }
    }

    // ---- row-sum reduce across t-residues (lanes 0..15 of each group) ----
#pragma unroll
    for (int si = 0; si < 2; si++)
#pragma unroll
        for (int r = 0; r < 4; r++) {
            float t = rp[si][r];
            t += __shfl_xor(t, 1);
            t += __shfl_xor(t, 2);
            t += __shfl_xor(t, 4);
            t += __shfl_xor(t, 8);
            if (l15 == 0) srow[S0 + 16 * si + 4 * g + r] = t;
        }
    __syncthreads();   // barrier1: Mb + srow complete; Xb(K) free

    // ---- M_norm; stage V^T into Xb ----
    if (p0) smn[tid] = fmaxf(fabsf(srow[tid] + sintern[tid]), sengs[tid]);
    {
        int t  = tid >> 1;
        int vh = (tid & 1) * 64;
        const float* src = vp + (size_t)t * Vv + vh;
#pragma unroll
        for (int i = 0; i < 16; i++) {
            float4 f = *(const float4*)&src[4 * i];
            float vals[4] = { f.x, f.y, f.z, f.w };
#pragma unroll
            for (int j = 0; j < 4; j++) {
                int vv = vh + 4 * i + j;
                Xb[vv * Kk + (t ^ ((vv & 7) << 3))] = (_Float16)vals[j];
            }
        }
    }
    __syncthreads();   // barrier2: V^T staged, smn ready

    // ---- PV: hacc[s][v] += sum_t M[s,t] V[t,v] ----
    f32x4 hacc[2][8];
#pragma unroll
    for (int si = 0; si < 2; si++)
#pragma unroll
        for (int vj = 0; vj < 8; vj++) hacc[si][vj] = (f32x4){0.f, 0.f, 0.f, 0.f};

    for (int kkt = 0; kkt <= w; kkt++) {
        f16x8 af[2];
#pragma unroll
        for (int si = 0; si < 2; si++) {
            int sr = S0 + 16 * si + l15;
            af[si] = *(const f16x8*)&Mb[sr * Ss + ((kkt * 32 + g * 8) ^ swt)];
        }
#pragma unroll
        for (int vj = 0; vj < 8; vj++) {
            int vr = vj * 16 + l15;
            f16x8 bv = *(const f16x8*)&Xb[vr * Kk + ((kkt * 32 + g * 8) ^ swt)];
            hacc[0][vj] = __builtin_amdgcn_mfma_f32_16x16x32_f16(af[0], bv, hacc[0][vj], 0, 0, 0);
            hacc[1][vj] = __builtin_amdgcn_mfma_f32_16x16x32_f16(af[1], bv, hacc[1][vj], 0, 0, 0);
        }
    }
    __syncthreads();   // barrier3: done reading Xb(V^T)

    // ---- stage c_prev^T into Xb ----
    {
        int kr = tid >> 1;
        int vh = (tid & 1) * 64;
        const float* src = cprev + (size_t)kr * Vv + vh;
#pragma unroll
        for (int i = 0; i < 16; i++) {
            float4 f = *(const float4*)&src[4 * i];
            float vals[4] = { f.x, f.y, f.z, f.w };
#pragma unroll
            for (int j = 0; j < 4; j++) {
                int vv = vh + 4 * i + j;
                Xb[vv * Kk + (kr ^ ((vv & 7) << 3))] = (_Float16)vals[j];
            }
        }
    }
    __syncthreads();   // barrier4: c_prev^T staged

    // ---- inter: hacc += iw[s] * sum_k q[s,k] c_prev[k,v] ----
    for (int vj = 0; vj < 8; vj++) {
        int vr = vj * 16 + l15;
        f16x8 bcf[4];
#pragma unroll
        for (int kk = 0; kk < 4; kk++)
            bcf[kk] = *(const f16x8*)&Xb[vr * Kk + ((kk * 32 + g * 8) ^ swt)];
#pragma unroll
        for (int si = 0; si < 2; si++) {
            f32x4 tmp = {0.f, 0.f, 0.f, 0.f};
#pragma unroll
            for (int kk = 0; kk < 4; kk++)
                tmp = __builtin_amdgcn_mfma_f32_16x16x32_f16(qf[si][kk], bcf[kk], tmp, 0, 0, 0);
#pragma unroll
            for (int r = 0; r < 4; r++)
                hacc[si][vj][r] += tmp[r] * siwr[si][r];
        }
    }

    // ---- output: h = hacc / M_norm ----
    float rnv[2][4];
#pragma unroll
    for (int si = 0; si < 2; si++)
#pragma unroll
        for (int r = 0; r < 4; r++)
            rnv[si][r] = 1.0f / smn[S0 + 16 * si + 4 * g + r];

#pragma unroll
    for (int si = 0; si < 2; si++)
#pragma unroll
        for (int vj = 0; vj < 8; vj++)
#pragma unroll
            for (int r = 0; r < 4; r++) {
                int sr = S0 + 16 * si + 4 * g + r;
                out[(rowbase + sr) * Vv + vj * 16 + l15] = hacc[si][vj][r] * rnv[si][r];
            }
}

// ---------------------------------------------------------------------------
extern "C" void kernel_launch(void* const* d_in, const int* in_sizes, int n_in,
                              void* d_out, int out_size, void* d_ws, size_t ws_size,
                              hipStream_t stream) {
    (void)in_sizes; (void)n_in; (void)out_size; (void)ws_size;
    const float* q  = (const float*)d_in[0];
    const float* k  = (const float*)d_in[1];
    const float* v  = (const float*)d_in[2];
    const float* ig = (const float*)d_in[3];
    const float* fg = (const float*)d_in[4];
    const float* C0 = (const float*)d_in[5];
    const float* n0 = (const float*)d_in[6];
    const float* m0 = (const float*)d_in[7];
    float* out = (float*)d_out;
    float* ws  = (float*)d_ws;

    k_gates<<<BH * Cc, Ss, 0, stream>>>(ig, fg, ws);
    k_kv_mfma<<<BH * Cc, 256, 0, stream>>>(k, v, ws);
    k_scan_coef<<<1, 64, 0, stream>>>(m0, ws);
    k_scan_apply<<<(BH * Kk * Vv) / 256 + (BH * Kk) / 256, 256, 0, stream>>>(C0, n0, ws);
    k_out_mfma<<<BH * Cc, 256, 0, stream>>>(q, k, v, ig, ws, out);
}

// Round 6
// 78.080 us; speedup vs baseline: 3.0339x; 1.0599x over previous
//
#include <hip/hip_runtime.h>
#include <hip/hip_fp16.h>
#include <math.h>

#define Bb 2
#define Hh 8
#define Tt 4096
#define Kk 128
#define Vv 128
#define Ss 128
#define Cc 32
#define BH (Bb*Hh)
#define SCALE 0.08838834764831845f  /* 1/sqrt(128) */

// ---- workspace layout (in floats) ----
#define OFF_LFACC  0
#define OFF_FGEXP  (OFF_LFACC + BH*Tt)            // 65536
#define OFF_LFLAST (OFF_FGEXP + BH*Tt)            // 131072
#define OFF_MINTRA (OFF_LFLAST + BH*Cc)           // 131584
#define OFF_MPREV  (OFF_MINTRA + BH*Cc)           // 132096
#define OFF_E1     (OFF_MPREV + BH*Cc)            // 132608
#define OFF_E2     (OFF_E1 + BH*Cc)               // 133120
#define OFF_KV     (OFF_E2 + BH*Cc)               // 133632  (becomes c_prev)
#define OFF_KSUM   (OFF_KV + (size_t)BH*Cc*Kk*Vv) // 8522240 (becomes n_prev)

typedef _Float16 f16x8 __attribute__((ext_vector_type(8)));
typedef _Float16 f16x4 __attribute__((ext_vector_type(4)));
typedef float f32x4 __attribute__((ext_vector_type(4)));

// ---------------------------------------------------------------------------
// Kernel 1: per-chunk gates (unchanged)
// ---------------------------------------------------------------------------
__global__ __launch_bounds__(128) void k_gates(const float* __restrict__ ig,
                                               const float* __restrict__ fg,
                                               float* __restrict__ ws) {
    int blk = blockIdx.x;
    int bh = blk >> 5;
    int c  = blk & 31;
    int t  = threadIdx.x;
    int gidx = bh * Tt + c * Ss + t;

    float x  = fg[gidx];
    float lf = fminf(x, 0.f) - log1pf(expf(-fabsf(x)));

    __shared__ float sbuf[Ss];
    __shared__ float red[Ss];
    sbuf[t] = lf;
    __syncthreads();
    for (int off = 1; off < Ss; off <<= 1) {
        float vv_ = (t >= off) ? sbuf[t - off] : 0.f;
        __syncthreads();
        sbuf[t] += vv_;
        __syncthreads();
    }
    float lfacc  = sbuf[t];
    float lflast = sbuf[Ss - 1];
    float iv  = ig[gidx];
    float fwd = iv + lflast - lfacc;

    red[t] = fwd;
    __syncthreads();
    for (int off = Ss / 2; off > 0; off >>= 1) {
        if (t < off) red[t] = fmaxf(red[t], red[t + off]);
        __syncthreads();
    }
    float mi = red[0];

    ws[OFF_LFACC + gidx] = lfacc;
    ws[OFF_FGEXP + gidx] = expf(fwd - mi);
    if (t == 0) {
        ws[OFF_LFLAST + blk] = lflast;
        ws[OFF_MINTRA + blk] = mi;
    }
}

// ---------------------------------------------------------------------------
// Kernel 2 (v2): MFMA kv + ksum, 512 threads (8 waves, 4 waves/SIMD).
// Staging: 4x4 register-tile transpose, b64 LDS writes (16x fewer LDS ops
// than scalar). Swizzle col ^= (row&15)<<3 (more bank groups on transposed
// writes than &7; reads stay at b128 phase-minimum).
// Wave w computes kidx band [16w,16w+16); 32 MFMAs/wave.
// ---------------------------------------------------------------------------
__global__ __launch_bounds__(512, 4) void k_kv_mfma(const float* __restrict__ kg,
                                                    const float* __restrict__ vg,
                                                    float* __restrict__ ws) {
    __shared__ _Float16 Kt[Ss * Ss];   // (g*K)^T [kidx][t], swizzled
    __shared__ _Float16 Vt[Ss * Ss];   // V^T [vidx][t], swizzled
    __shared__ float sfg[Ss];

    int blk = blockIdx.x;
    int bh = blk >> 5;
    int c  = blk & 31;
    int tid = threadIdx.x;
    int lane = tid & 63;
    int w = tid >> 6;                  // wave 0..7
    int l15 = lane & 15;
    int g = lane >> 4;

    const float* kb = kg + ((size_t)bh * Tt + (size_t)c * Ss) * Kk;
    const float* vb = vg + ((size_t)bh * Tt + (size_t)c * Ss) * Vv;

    if (tid < Ss) sfg[tid] = ws[OFF_FGEXP + bh * Tt + c * Ss + tid];
    __syncthreads();

    // ---- stage: 2 tiles (4x4) per thread per array, register transpose ----
#pragma unroll
    for (int rep = 0; rep < 2; rep++) {
        int tau = tid + rep * 512;          // 0..1023
        int c0 = (tau & 31) * 4;            // col (kidx/vidx) base
        int t0 = (tau >> 5) * 4;            // row (t) base
        const float* ksrc = kb + (size_t)t0 * Kk + c0;
        const float* vsrc = vb + (size_t)t0 * Vv + c0;
        float4 k0 = *(const float4*)(ksrc);
        float4 k1 = *(const float4*)(ksrc + Kk);
        float4 k2 = *(const float4*)(ksrc + 2 * Kk);
        float4 k3 = *(const float4*)(ksrc + 3 * Kk);
        float4 v0 = *(const float4*)(vsrc);
        float4 v1 = *(const float4*)(vsrc + Vv);
        float4 v2 = *(const float4*)(vsrc + 2 * Vv);
        float4 v3 = *(const float4*)(vsrc + 3 * Vv);
        float g0 = sfg[t0], g1 = sfg[t0 + 1], g2 = sfg[t0 + 2], g3 = sfg[t0 + 3];
#pragma unroll
        for (int jc = 0; jc < 4; jc++) {
            float ke0 = (jc == 0 ? k0.x : jc == 1 ? k0.y : jc == 2 ? k0.z : k0.w);
            float ke1 = (jc == 0 ? k1.x : jc == 1 ? k1.y : jc == 2 ? k1.z : k1.w);
            float ke2 = (jc == 0 ? k2.x : jc == 1 ? k2.y : jc == 2 ? k2.z : k2.w);
            float ke3 = (jc == 0 ? k3.x : jc == 1 ? k3.y : jc == 2 ? k3.z : k3.w);
            float ve0 = (jc == 0 ? v0.x : jc == 1 ? v0.y : jc == 2 ? v0.z : v0.w);
            float ve1 = (jc == 0 ? v1.x : jc == 1 ? v1.y : jc == 2 ? v1.z : v1.w);
            float ve2 = (jc == 0 ? v2.x : jc == 1 ? v2.y : jc == 2 ? v2.z : v2.w);
            float ve3 = (jc == 0 ? v3.x : jc == 1 ? v3.y : jc == 2 ? v3.z : v3.w);
            int row = c0 + jc;
            int col = t0 ^ ((row & 15) << 3);
            f16x4 kc = { (_Float16)(ke0 * g0), (_Float16)(ke1 * g1),
                         (_Float16)(ke2 * g2), (_Float16)(ke3 * g3) };
            f16x4 vc = { (_Float16)ve0, (_Float16)ve1,
                         (_Float16)ve2, (_Float16)ve3 };
            *(f16x4*)&Kt[row * Ss + col] = kc;
            *(f16x4*)&Vt[row * Ss + col] = vc;
        }
    }
    __syncthreads();

    // ---- ksum: per-row reduction of Kt (threads 0..127) ----
    if (tid < Ss) {
        int sw = (tid & 15) << 3;
        float s = 0.f;
#pragma unroll
        for (int i = 0; i < 16; i++) {
            f16x8 ld = *(const f16x8*)&Kt[tid * Ss + ((8 * i) ^ sw)];
#pragma unroll
            for (int e = 0; e < 8; e++) s += (float)ld[e];
        }
        ws[OFF_KSUM + (size_t)blk * Kk + tid] = s;
    }

    // ---- MFMA: wave w -> kidx band [16w, 16w+16) ----
    const int band = w * 16;
    const int swt = l15 << 3;          // (row&15)<<3 with row%16 == l15
    f16x8 af[4];
#pragma unroll
    for (int kk = 0; kk < 4; kk++)
        af[kk] = *(const f16x8*)&Kt[(band + l15) * Ss + ((kk * 32 + g * 8) ^ swt)];

    f32x4 acc[8];
#pragma unroll
    for (int vj = 0; vj < 8; vj++) acc[vj] = (f32x4){0.f, 0.f, 0.f, 0.f};

#pragma unroll
    for (int vj = 0; vj < 8; vj++) {
        int vr = vj * 16 + l15;
#pragma unroll
        for (int kk = 0; kk < 4; kk++) {
            f16x8 bv = *(const f16x8*)&Vt[vr * Ss + ((kk * 32 + g * 8) ^ swt)];
            acc[vj] = __builtin_amdgcn_mfma_f32_16x16x32_f16(af[kk], bv, acc[vj], 0, 0, 0);
        }
    }

    // ---- write kv (fp32, row-major [kidx][vidx]) ----
    float* kvout = ws + OFF_KV + (size_t)blk * Kk * Vv;
#pragma unroll
    for (int vj = 0; vj < 8; vj++)
#pragma unroll
        for (int r = 0; r < 4; r++)
            kvout[(size_t)(band + 4 * g + r) * Vv + vj * 16 + l15] = acc[vj][r];
}

// ---------------------------------------------------------------------------
// Kernel 3a: scan coefficients. Reference quirk: carry max m is NEVER
// updated — m_prev == m0 for all chunks. Replicate exactly.
// ---------------------------------------------------------------------------
__global__ void k_scan_coef(const float* __restrict__ m0, float* __restrict__ ws) {
    int bh = threadIdx.x;
    if (bh >= BH) return;
    const float m = m0[bh];
    for (int c = 0; c < Cc; c++) {
        int blk = bh * Cc + c;
        float lfl = ws[OFF_LFLAST + blk];
        float mi  = ws[OFF_MINTRA + blk];
        float mn  = fmaxf(lfl + m, mi);
        ws[OFF_MPREV + blk] = m;
        ws[OFF_E1 + blk] = expf(lfl + m - mn);
        ws[OFF_E2 + blk] = expf(mi - mn);
    }
}

// ---------------------------------------------------------------------------
// Kernel 3b: scan application (unchanged)
// ---------------------------------------------------------------------------
__global__ __launch_bounds__(256) void k_scan_apply(const float* __restrict__ C0,
                                                    const float* __restrict__ n0,
                                                    float* __restrict__ ws) {
    const int NC = BH * Kk * Vv;
    int gid = blockIdx.x * 256 + threadIdx.x;
    if (gid < NC) {
        int bh  = gid / (Kk * Vv);
        int idx = gid % (Kk * Vv);
        float st = C0[gid];
        float* base = ws + OFF_KV + (size_t)bh * Cc * Kk * Vv + idx;
        const float* e1p = ws + OFF_E1 + bh * Cc;
        const float* e2p = ws + OFF_E2 + bh * Cc;
        for (int c = 0; c < Cc; c++) {
            float* p = base + (size_t)c * Kk * Vv;
            float kvv = *p;
            *p = st;
            st = st * e1p[c] + kvv * e2p[c];
        }
    } else {
        int g2 = gid - NC;
        int bh = g2 / Kk;
        float st = n0[g2];
        float* base = ws + OFF_KSUM + (size_t)bh * Cc * Kk + (g2 % Kk);
        const float* e1p = ws + OFF_E1 + bh * Cc;
        const float* e2p = ws + OFF_E2 + bh * Cc;
        for (int c = 0; c < Cc; c++) {
            float* p = base + (size_t)c * Kk;
            float kvv = *p;
            *p = st;
            st = st * e1p[c] + kvv * e2p[c];
        }
    }
}

// ---------------------------------------------------------------------------
// Kernel 4: MFMA intra-chunk scores + output — FP16 (unchanged)
// ---------------------------------------------------------------------------
__global__ __launch_bounds__(256, 2) void k_out_mfma(const float* __restrict__ qg,
                                                     const float* __restrict__ kg,
                                                     const float* __restrict__ vg,
                                                     const float* __restrict__ ig,
                                                     float* __restrict__ ws,
                                                     float* __restrict__ out) {
    __shared__ _Float16 Xb[Ss * Kk];    // staging: K, then V^T, then cprev^T
    __shared__ _Float16 Mb[Ss * Ss];    // gated scores, fp16, swizzled
    __shared__ float sbt[Ss], sas[Ss], siw[Ss], smn[Ss], srow[Ss];
    __shared__ float sintern[Ss], sengs[Ss], snp[Ss], sscan[Ss];

    int blk = blockIdx.x;
    int bh = blk >> 5;
    int c  = blk & 31;
    int tid = threadIdx.x;
    int lane = tid & 63;
    int w = tid >> 6;                   // wave id 0..3
    int l15 = lane & 15;
    int g = lane >> 4;                  // 0..3
    const int S0 = w * 32;
    const int swt = (l15 & 7) << 3;     // per-lane read swizzle (row&7 == l15&7)

    const size_t rowbase = (size_t)bh * Tt + (size_t)c * Ss;
    const float* qp = qg + rowbase * Kk;
    const float* kp = kg + rowbase * Kk;
    const float* vp = vg + rowbase * Vv;
    const float* nprev = ws + OFF_KSUM + (size_t)blk * Kk;
    const float* cprev = ws + OFF_KV + (size_t)blk * Kk * Vv;
    const float m_prev = ws[OFF_MPREV + blk];

    // ---- stage K into Xb (fp16, swizzled), row-major [t][k] ----
    {
        int t  = tid >> 1;
        int kh = (tid & 1) * 64;
        const float* src = kp + (size_t)t * Kk + kh;
        _Float16* dst = &Xb[t * Kk];
        int sw = (t & 7) << 3;
#pragma unroll
        for (int i = 0; i < 16; i++) {
            float4 f = *(const float4*)&src[4 * i];
            int col = (kh + 4 * i) ^ sw;
            f16x4 s4 = { (_Float16)f.x, (_Float16)f.y, (_Float16)f.z, (_Float16)f.w };
            *(f16x4*)&dst[col] = s4;
        }
    }

    // ---- load Q fragments (registers, reused for QK^T and inter) ----
    f16x8 qf[2][4];
#pragma unroll
    for (int si = 0; si < 2; si++) {
        int row = S0 + 16 * si + l15;
#pragma unroll
        for (int kk = 0; kk < 4; kk++) {
            const float* p = qp + (size_t)row * Kk + kk * 32 + g * 8;
            float4 a = *(const float4*)p;
            float4 b = *(const float4*)(p + 4);
            f16x8 r;
            r[0]=(_Float16)a.x; r[1]=(_Float16)a.y; r[2]=(_Float16)a.z; r[3]=(_Float16)a.w;
            r[4]=(_Float16)b.x; r[5]=(_Float16)b.y; r[6]=(_Float16)b.z; r[7]=(_Float16)b.w;
            qf[si][kk] = r;
        }
    }

    // ---- phase 0: stabilizers (threads 0..127) ----
    bool p0 = tid < Ss;
    float lfa = 0.f;
    if (p0) {
        lfa = ws[OFF_LFACC + bh * Tt + c * Ss + tid];
        float bt = ig[bh * Tt + c * Ss + tid] - lfa;
        sbt[tid] = bt;
        sscan[tid] = bt;
        snp[tid] = nprev[tid];
    }
    __syncthreads();
    for (int off = 1; off < Ss; off <<= 1) {
        float o = -3.4e38f;
        if (p0 && tid >= off) o = sscan[tid - off];
        __syncthreads();
        if (p0) sscan[tid] = fmaxf(sscan[tid], o);
        __syncthreads();
    }
    if (p0) {
        float mx = fmaxf(sscan[tid], m_prev);
        sas[tid] = -mx;
        siw[tid] = SCALE * __expf(m_prev - mx);
        sengs[tid] = __expf(-(lfa + mx));
    }
    __syncthreads();   // barrier0: Kb staged, phase0 arrays ready

    // ---- per-lane row constants ----
    float asr[2][4], siwr[2][4];
#pragma unroll
    for (int si = 0; si < 2; si++)
#pragma unroll
        for (int r = 0; r < 4; r++) {
            int sr = S0 + 16 * si + 4 * g + r;
            asr[si][r] = sas[sr];
            siwr[si][r] = siw[sr];
        }

    // ---- intern[s] = (q . n_prev) * iw, via q fragments ----
#pragma unroll
    for (int si = 0; si < 2; si++) {
        float d = 0.f;
#pragma unroll
        for (int kk = 0; kk < 4; kk++)
#pragma unroll
            for (int e = 0; e < 8; e++)
                d += (float)qf[si][kk][e] * snp[kk * 32 + g * 8 + e];
        d += __shfl_xor(d, 16);
        d += __shfl_xor(d, 32);
        if (g == 0) {
            int s = S0 + 16 * si + l15;
            sintern[s] = d * siw[s];
        }
    }

    // ---- QK^T + gating -> Mb (fp16) + row sums ----
    float rp[2][4];
#pragma unroll
    for (int si = 0; si < 2; si++)
#pragma unroll
        for (int r = 0; r < 4; r++) rp[si][r] = 0.f;

    for (int tj = 0; tj <= 2 * w + 1; tj++) {
        int trow = tj * 16 + l15;
        f16x8 bfr[4];
#pragma unroll
        for (int kk = 0; kk < 4; kk++)
            bfr[kk] = *(const f16x8*)&Xb[trow * Kk + ((kk * 32 + g * 8) ^ swt)];
        float btv = sbt[trow];
#pragma unroll
        for (int si = 0; si < 2; si++) {
            if (tj > 2 * w + si) {
                // fully-masked tile (si==0, tj==2w+1): zero-fill Mb
#pragma unroll
                for (int r = 0; r < 4; r++) {
                    int sr = S0 + 4 * g + r;   // si==0 here
                    Mb[sr * Ss + (trow ^ ((sr & 7) << 3))] = (_Float16)0.f;
                }
                continue;
            }
            f32x4 acc = {0.f, 0.f, 0.f, 0.f};
#pragma unroll
            for (int kk = 0; kk < 4; kk++)
                acc = __builtin_amdgcn_mfma_f32_16x16x32_f16(qf[si][kk], bfr[kk], acc, 0, 0, 0);
#pragma unroll
            for (int r = 0; r < 4; r++) {
                int sr = S0 + 16 * si + 4 * g + r;
                float val = 0.f;
                if (trow <= sr) {
                    val = acc[r] * SCALE * __expf(asr[si][r] + btv);
                    rp[si][r] += val;
                }
                Mb[sr * Ss + (trow ^ ((sr & 7) << 3))] = (_Float16)val;
            }
        }
    }

    // ---- row-sum reduce across t-residues (lanes 0..15 of each group) ----
#pragma unroll
    for (int si = 0; si < 2; si++)
#pragma unroll
        for (int r = 0; r < 4; r++) {
            float t = rp[si][r];
            t += __shfl_xor(t, 1);
            t += __shfl_xor(t, 2);
            t += __shfl_xor(t, 4);
            t += __shfl_xor(t, 8);
            if (l15 == 0) srow[S0 + 16 * si + 4 * g + r] = t;
        }
    __syncthreads();   // barrier1: Mb + srow complete; Xb(K) free

    // ---- M_norm; stage V^T into Xb ----
    if (p0) smn[tid] = fmaxf(fabsf(srow[tid] + sintern[tid]), sengs[tid]);
    {
        int t  = tid >> 1;
        int vh = (tid & 1) * 64;
        const float* src = vp + (size_t)t * Vv + vh;
#pragma unroll
        for (int i = 0; i < 16; i++) {
            float4 f = *(const float4*)&src[4 * i];
            float vals[4] = { f.x, f.y, f.z, f.w };
#pragma unroll
            for (int j = 0; j < 4; j++) {
                int vv = vh + 4 * i + j;
                Xb[vv * Kk + (t ^ ((vv & 7) << 3))] = (_Float16)vals[j];
            }
        }
    }
    __syncthreads();   // barrier2: V^T staged, smn ready

    // ---- PV: hacc[s][v] += sum_t M[s,t] V[t,v] ----
    f32x4 hacc[2][8];
#pragma unroll
    for (int si = 0; si < 2; si++)
#pragma unroll
        for (int vj = 0; vj < 8; vj++) hacc[si][vj] = (f32x4){0.f, 0.f, 0.f, 0.f};

    for (int kkt = 0; kkt <= w; kkt++) {
        f16x8 af[2];
#pragma unroll
        for (int si = 0; si < 2; si++) {
            int sr = S0 + 16 * si + l15;
            af[si] = *(const f16x8*)&Mb[sr * Ss + ((kkt * 32 + g * 8) ^ swt)];
        }
#pragma unroll
        for (int vj = 0; vj < 8; vj++) {
            int vr = vj * 16 + l15;
            f16x8 bv = *(const f16x8*)&Xb[vr * Kk + ((kkt * 32 + g * 8) ^ swt)];
            hacc[0][vj] = __builtin_amdgcn_mfma_f32_16x16x32_f16(af[0], bv, hacc[0][vj], 0, 0, 0);
            hacc[1][vj] = __builtin_amdgcn_mfma_f32_16x16x32_f16(af[1], bv, hacc[1][vj], 0, 0, 0);
        }
    }
    __syncthreads();   // barrier3: done reading Xb(V^T)

    // ---- stage c_prev^T into Xb ----
    {
        int kr = tid >> 1;
        int vh = (tid & 1) * 64;
        const float* src = cprev + (size_t)kr * Vv + vh;
#pragma unroll
        for (int i = 0; i < 16; i++) {
            float4 f = *(const float4*)&src[4 * i];
            float vals[4] = { f.x, f.y, f.z, f.w };
#pragma unroll
            for (int j = 0; j < 4; j++) {
                int vv = vh + 4 * i + j;
                Xb[vv * Kk + (kr ^ ((vv & 7) << 3))] = (_Float16)vals[j];
            }
        }
    }
    __syncthreads();   // barrier4: c_prev^T staged

    // ---- inter: hacc += iw[s] * sum_k q[s,k] c_prev[k,v] ----
    for (int vj = 0; vj < 8; vj++) {
        int vr = vj * 16 + l15;
        f16x8 bcf[4];
#pragma unroll
        for (int kk = 0; kk < 4; kk++)
            bcf[kk] = *(const f16x8*)&Xb[vr * Kk + ((kk * 32 + g * 8) ^ swt)];
#pragma unroll
        for (int si = 0; si < 2; si++) {
            f32x4 tmp = {0.f, 0.f, 0.f, 0.f};
#pragma unroll
            for (int kk = 0; kk < 4; kk++)
                tmp = __builtin_amdgcn_mfma_f32_16x16x32_f16(qf[si][kk], bcf[kk], tmp, 0, 0, 0);
#pragma unroll
            for (int r = 0; r < 4; r++)
                hacc[si][vj][r] += tmp[r] * siwr[si][r];
        }
    }

    // ---- output: h = hacc / M_norm ----
    float rnv[2][4];
#pragma unroll
    for (int si = 0; si < 2; si++)
#pragma unroll
        for (int r = 0; r < 4; r++)
            rnv[si][r] = 1.0f / smn[S0 + 16 * si + 4 * g + r];

#pragma unroll
    for (int si = 0; si < 2; si++)
#pragma unroll
        for (int vj = 0; vj < 8; vj++)
#pragma unroll
            for (int r = 0; r < 4; r++) {
                int sr = S0 + 16 * si + 4 * g + r;
                out[(rowbase + sr) * Vv + vj * 16 + l15] = hacc[si][vj][r] * rnv[si][r];
            }
}

// ---------------------------------------------------------------------------
extern "C" void kernel_launch(void* const* d_in, const int* in_sizes, int n_in,
                              void* d_out, int out_size, void* d_ws, size_t ws_size,
                              hipStream_t stream) {
    (void)in_sizes; (void)n_in; (void)out_size; (void)ws_size;
    const float* q  = (const float*)d_in[0];
    const float* k  = (const float*)d_in[1];
    const float* v  = (const float*)d_in[2];
    const float* ig = (const float*)d_in[3];
    const float* fg = (const float*)d_in[4];
    const float* C0 = (const float*)d_in[5];
    const float* n0 = (const float*)d_in[6];
    const float* m0 = (const float*)d_in[7];
    float* out = (float*)d_out;
    float* ws  = (float*)d_ws;

    k_gates<<<BH * Cc, Ss, 0, stream>>>(ig, fg, ws);
    k_kv_mfma<<<BH * Cc, 512, 0, stream>>>(k, v, ws);
    k_scan_coef<<<1, 64, 0, stream>>>(m0, ws);
    k_scan_apply<<<(BH * Kk * Vv) / 256 + (BH * Kk) / 256, 256, 0, stream>>>(C0, n0, ws);
    k_out_mfma<<<BH * Cc, 256, 0, stream>>>(q, k, v, ig, ws, out);
}

// Round 7
// 70.889 us; speedup vs baseline: 3.3417x; 1.1014x over previous
//
#include <hip/hip_runtime.h>
#include <hip/hip_fp16.h>
#include <math.h>

#define Bb 2
#define Hh 8
#define Tt 4096
#define Kk 128
#define Vv 128
#define Ss 128
#define Cc 32
#define BH (Bb*Hh)
#define SCALE 0.08838834764831845f  /* 1/sqrt(128) */

// ---- workspace layout ----
// fp32 region (float indices):
#define OFF_LFACC  0                               // BH*Tt
#define OFF_LFLAST (OFF_LFACC + BH*Tt)             // BH*Cc
#define OFF_MINTRA (OFF_LFLAST + BH*Cc)
#define OFF_MPREV  (OFF_MINTRA + BH*Cc)
#define OFF_E1     (OFF_MPREV + BH*Cc)
#define OFF_E2     (OFF_E1 + BH*Cc)
#define OFF_KSUM   (OFF_E2 + BH*Cc)                // BH*Cc*Kk (fp32, becomes n_prev)
#define OFF_KVH    (OFF_KSUM + BH*Cc*Kk)           // fp16 region starts here:
                                                   // kv^T [blk][v][k], BH*Cc*Kk*Vv halves
                                                   // (becomes c_prev^T after scan)

typedef _Float16 f16x8 __attribute__((ext_vector_type(8)));
typedef _Float16 f16x4 __attribute__((ext_vector_type(4)));
typedef _Float16 f16x2 __attribute__((ext_vector_type(2)));
typedef float f32x4 __attribute__((ext_vector_type(4)));

// ---------------------------------------------------------------------------
// Kernel 1 (fused): gates + MFMA kv^T (fp16) + ksum. 512 threads, 8 waves.
// gates: wave-level shfl cumsum/max (3 barriers, no Hillis-Steele).
// kv^T[v][k] = sum_t v[t,v] * (k[t,k]*g[t])  — MFMA with A=Vt, B=Kt.
// Staging: 4x4 register-tile transpose, b64 LDS writes, swizzle (row&15)<<3.
// ---------------------------------------------------------------------------
__global__ __launch_bounds__(512, 4) void k_kvg(const float* __restrict__ ig,
                                                const float* __restrict__ fg,
                                                const float* __restrict__ kg,
                                                const float* __restrict__ vg,
                                                float* __restrict__ ws) {
    __shared__ _Float16 Kt[Ss * Ss];   // (g*K)^T [kidx][t], swizzled
    __shared__ _Float16 Vt[Ss * Ss];   // V^T [vidx][t], swizzled
    __shared__ float sfg[Ss];
    __shared__ float scomb[4];

    int blk = blockIdx.x;
    int bh = blk >> 5;
    int c  = blk & 31;
    int tid = threadIdx.x;
    int lane = tid & 63;
    int w = tid >> 6;                  // wave 0..7
    int l15 = lane & 15;
    int g = lane >> 4;

    const float* kb = kg + ((size_t)bh * Tt + (size_t)c * Ss) * Kk;
    const float* vb = vg + ((size_t)bh * Tt + (size_t)c * Ss) * Vv;

    // ---- gates (threads 0..127, shfl-based scan) ----
    bool p0 = tid < Ss;
    int lane64 = tid & 63;
    int wv = (tid >> 6) & 1;
    int gidx = bh * Tt + c * Ss + tid;
    float lfacc = 0.f, fwd = 0.f;
    if (p0) {
        float x  = fg[gidx];
        lfacc = fminf(x, 0.f) - log1pf(__expf(-fabsf(x)));   // lf
        for (int off = 1; off < 64; off <<= 1) {
            float o = __shfl_up(lfacc, off);
            if (lane64 >= off) lfacc += o;
        }
        if (lane64 == 63) scomb[wv] = lfacc;
    }
    __syncthreads();
    if (p0) {
        float tot0 = scomb[0];
        if (wv == 1) lfacc += tot0;
        float lflast = tot0 + scomb[1];
        fwd = ig[gidx] + lflast - lfacc;
        float mx = fwd;
        for (int off = 32; off; off >>= 1) mx = fmaxf(mx, __shfl_xor(mx, off));
        if (lane64 == 0) scomb[2 + wv] = mx;
    }
    __syncthreads();
    if (p0) {
        float mi = fmaxf(scomb[2], scomb[3]);
        sfg[tid] = __expf(fwd - mi);
        ws[OFF_LFACC + gidx] = lfacc;
        if (tid == 0) {
            ws[OFF_LFLAST + blk] = scomb[0] + scomb[1];
            ws[OFF_MINTRA + blk] = mi;
        }
    }
    __syncthreads();

    // ---- stage: 2 tiles (4x4) per thread per array, register transpose ----
#pragma unroll
    for (int rep = 0; rep < 2; rep++) {
        int tau = tid + rep * 512;          // 0..1023
        int c0 = (tau & 31) * 4;            // col (kidx/vidx) base
        int t0 = (tau >> 5) * 4;            // row (t) base
        const float* ksrc = kb + (size_t)t0 * Kk + c0;
        const float* vsrc = vb + (size_t)t0 * Vv + c0;
        float4 k0 = *(const float4*)(ksrc);
        float4 k1 = *(const float4*)(ksrc + Kk);
        float4 k2 = *(const float4*)(ksrc + 2 * Kk);
        float4 k3 = *(const float4*)(ksrc + 3 * Kk);
        float4 v0 = *(const float4*)(vsrc);
        float4 v1 = *(const float4*)(vsrc + Vv);
        float4 v2 = *(const float4*)(vsrc + 2 * Vv);
        float4 v3 = *(const float4*)(vsrc + 3 * Vv);
        float g0 = sfg[t0], g1 = sfg[t0 + 1], g2 = sfg[t0 + 2], g3 = sfg[t0 + 3];
#pragma unroll
        for (int jc = 0; jc < 4; jc++) {
            float ke0 = (jc == 0 ? k0.x : jc == 1 ? k0.y : jc == 2 ? k0.z : k0.w);
            float ke1 = (jc == 0 ? k1.x : jc == 1 ? k1.y : jc == 2 ? k1.z : k1.w);
            float ke2 = (jc == 0 ? k2.x : jc == 1 ? k2.y : jc == 2 ? k2.z : k2.w);
            float ke3 = (jc == 0 ? k3.x : jc == 1 ? k3.y : jc == 2 ? k3.z : k3.w);
            float ve0 = (jc == 0 ? v0.x : jc == 1 ? v0.y : jc == 2 ? v0.z : v0.w);
            float ve1 = (jc == 0 ? v1.x : jc == 1 ? v1.y : jc == 2 ? v1.z : v1.w);
            float ve2 = (jc == 0 ? v2.x : jc == 1 ? v2.y : jc == 2 ? v2.z : v2.w);
            float ve3 = (jc == 0 ? v3.x : jc == 1 ? v3.y : jc == 2 ? v3.z : v3.w);
            int row = c0 + jc;
            int col = t0 ^ ((row & 15) << 3);
            f16x4 kc = { (_Float16)(ke0 * g0), (_Float16)(ke1 * g1),
                         (_Float16)(ke2 * g2), (_Float16)(ke3 * g3) };
            f16x4 vc = { (_Float16)ve0, (_Float16)ve1,
                         (_Float16)ve2, (_Float16)ve3 };
            *(f16x4*)&Kt[row * Ss + col] = kc;
            *(f16x4*)&Vt[row * Ss + col] = vc;
        }
    }
    __syncthreads();

    // ---- ksum: per-row reduction of Kt (threads 0..127) ----
    if (tid < Ss) {
        int sw = (tid & 15) << 3;
        float s = 0.f;
#pragma unroll
        for (int i = 0; i < 16; i++) {
            f16x8 ld = *(const f16x8*)&Kt[tid * Ss + ((8 * i) ^ sw)];
#pragma unroll
            for (int e = 0; e < 8; e++) s += (float)ld[e];
        }
        ws[OFF_KSUM + (size_t)blk * Kk + tid] = s;
    }

    // ---- MFMA (swapped): wave w -> vidx band [16w, 16w+16) ----
    const int band = w * 16;
    const int swt = l15 << 3;
    f16x8 af[4];
#pragma unroll
    for (int kk = 0; kk < 4; kk++)
        af[kk] = *(const f16x8*)&Vt[(band + l15) * Ss + ((kk * 32 + g * 8) ^ swt)];

    f32x4 acc[8];
#pragma unroll
    for (int kj = 0; kj < 8; kj++) acc[kj] = (f32x4){0.f, 0.f, 0.f, 0.f};

#pragma unroll
    for (int kj = 0; kj < 8; kj++) {
        int kr = kj * 16 + l15;
#pragma unroll
        for (int kk = 0; kk < 4; kk++) {
            f16x8 bv = *(const f16x8*)&Kt[kr * Ss + ((kk * 32 + g * 8) ^ swt)];
            acc[kj] = __builtin_amdgcn_mfma_f32_16x16x32_f16(af[kk], bv, acc[kj], 0, 0, 0);
        }
    }

    // ---- write kv^T fp16 [v][k] ----
    _Float16* dst = (_Float16*)(ws + OFF_KVH) + (size_t)blk * Kk * Vv;
#pragma unroll
    for (int kj = 0; kj < 8; kj++)
#pragma unroll
        for (int r = 0; r < 4; r++)
            dst[(size_t)(band + 4 * g + r) * Kk + kj * 16 + l15] = (_Float16)acc[kj][r];
}

// ---------------------------------------------------------------------------
// Kernel 2a: scan coefficients. Reference quirk: carry max m is NEVER
// updated — m_prev == m0 for all chunks. Replicate exactly.
// ---------------------------------------------------------------------------
__global__ void k_scan_coef(const float* __restrict__ m0, float* __restrict__ ws) {
    int bh = threadIdx.x;
    if (bh >= BH) return;
    const float m = m0[bh];
    for (int c = 0; c < Cc; c++) {
        int blk = bh * Cc + c;
        float lfl = ws[OFF_LFLAST + blk];
        float mi  = ws[OFF_MINTRA + blk];
        float mn  = fmaxf(lfl + m, mi);
        ws[OFF_MPREV + blk] = m;
        ws[OFF_E1 + blk] = expf(lfl + m - mn);
        ws[OFF_E2 + blk] = expf(mi - mn);
    }
}

// ---------------------------------------------------------------------------
// Kernel 2b: scan application on fp16 kv^T (carry kept fp32 in registers).
// In-place: kv^T -> c_prev^T. C0 is [k][v] so the seed read is transposed.
// grid = (BH*K*V/2 + BH*K)/256 = 520 blocks.
// ---------------------------------------------------------------------------
__global__ __launch_bounds__(256) void k_scan_apply(const float* __restrict__ C0,
                                                    const float* __restrict__ n0,
                                                    float* __restrict__ ws) {
    const int NC2 = BH * Kk * Vv / 2;     // 131072 f16x2 elements
    int gid = blockIdx.x * 256 + threadIdx.x;
    if (gid < NC2) {
        int bh = gid >> 13;               // / (Kk*Vv/2)
        int i  = gid & 8191;
        int v  = i >> 6;
        int k2 = (i & 63) << 1;
        float st0 = C0[(size_t)bh * Kk * Vv + (size_t)k2 * Vv + v];
        float st1 = C0[(size_t)bh * Kk * Vv + (size_t)(k2 + 1) * Vv + v];
        f16x2* base = (f16x2*)((_Float16*)(ws + OFF_KVH) +
                               (size_t)bh * Cc * Kk * Vv + (size_t)v * Kk + k2);
        const float* e1p = ws + OFF_E1 + bh * Cc;
        const float* e2p = ws + OFF_E2 + bh * Cc;
        for (int c = 0; c < Cc; c++) {
            f16x2* p = base + (size_t)c * (Kk * Vv / 2);
            f16x2 kvv = *p;
            f16x2 o = { (_Float16)st0, (_Float16)st1 };
            *p = o;                        // c_prev^T for chunk c
            st0 = st0 * e1p[c] + (float)kvv[0] * e2p[c];
            st1 = st1 * e1p[c] + (float)kvv[1] * e2p[c];
        }
    } else if (gid < NC2 + BH * Kk) {
        int g2 = gid - NC2;
        int bh = g2 / Kk;
        float st = n0[g2];
        float* base = ws + OFF_KSUM + (size_t)bh * Cc * Kk + (g2 % Kk);
        const float* e1p = ws + OFF_E1 + bh * Cc;
        const float* e2p = ws + OFF_E2 + bh * Cc;
        for (int c = 0; c < Cc; c++) {
            float* p = base + (size_t)c * Kk;
            float kvv = *p;
            *p = st;                       // n_prev for chunk c
            st = st * e1p[c] + kvv * e2p[c];
        }
    }
}

// ---------------------------------------------------------------------------
// Kernel 3: MFMA intra-chunk scores + output. 512 threads = 8 waves,
// wave w owns s-tile [16w,16w+16). c_prev^T B-frags read DIRECTLY from HBM
// (fp16, k-contiguous) — no LDS staging for it. 4 barriers total.
// ---------------------------------------------------------------------------
__global__ __launch_bounds__(512, 4) void k_out_mfma(const float* __restrict__ qg,
                                                     const float* __restrict__ kg,
                                                     const float* __restrict__ vg,
                                                     const float* __restrict__ ig,
                                                     float* __restrict__ ws,
                                                     float* __restrict__ out) {
    __shared__ _Float16 Xb[Ss * Kk];    // staging: K [t][k], then V^T [v][t]
    __shared__ _Float16 Mb[Ss * Ss];    // gated scores, fp16, swizzled
    __shared__ float sbt[Ss], sas[Ss], siw[Ss], smn[Ss], srow[Ss];
    __shared__ float sintern[Ss], sengs[Ss], snp[Ss];
    __shared__ float scomb[2];

    int blk = blockIdx.x;
    int bh = blk >> 5;
    int c  = blk & 31;
    int tid = threadIdx.x;
    int lane = tid & 63;
    int w = tid >> 6;                   // wave id 0..7
    int l15 = lane & 15;
    int g = lane >> 4;                  // 0..3
    const int S0 = w * 16;
    const int swt = (l15 & 7) << 3;

    const size_t rowbase = (size_t)bh * Tt + (size_t)c * Ss;
    const float* qp = qg + rowbase * Kk;
    const float* kp = kg + rowbase * Kk;
    const float* vp = vg + rowbase * Vv;
    const float* nprev = ws + OFF_KSUM + (size_t)blk * Kk;
    const _Float16* cprevT = (const _Float16*)(ws + OFF_KVH) + (size_t)blk * Kk * Vv;
    const float m_prev = ws[OFF_MPREV + blk];

    // ---- stage K into Xb [t][k] fp16 swizzled (no transpose needed) ----
    {
        int t  = tid >> 2;
        int kh = (tid & 3) * 32;
        const float* src = kp + (size_t)t * Kk + kh;
        int sw = (t & 7) << 3;
#pragma unroll
        for (int i = 0; i < 8; i++) {
            float4 f = *(const float4*)&src[4 * i];
            int col = (kh + 4 * i) ^ sw;
            f16x4 s4 = { (_Float16)f.x, (_Float16)f.y, (_Float16)f.z, (_Float16)f.w };
            *(f16x4*)&Xb[t * Kk + col] = s4;
        }
    }

    // ---- Q fragments for own s-tile ----
    f16x8 qf[4];
    {
        int row = S0 + l15;
#pragma unroll
        for (int kk = 0; kk < 4; kk++) {
            const float* p = qp + (size_t)row * Kk + kk * 32 + g * 8;
            float4 a = *(const float4*)p;
            float4 b = *(const float4*)(p + 4);
            f16x8 r;
            r[0]=(_Float16)a.x; r[1]=(_Float16)a.y; r[2]=(_Float16)a.z; r[3]=(_Float16)a.w;
            r[4]=(_Float16)b.x; r[5]=(_Float16)b.y; r[6]=(_Float16)b.z; r[7]=(_Float16)b.w;
            qf[kk] = r;
        }
    }

    // ---- phase 0 part 1: bt + wave-shfl prefix max (threads 0..127) ----
    bool p0 = tid < Ss;
    int lane64 = tid & 63;
    int wv = (tid >> 6) & 1;
    float lfa = 0.f, pm = 0.f;
    if (p0) {
        lfa = ws[OFF_LFACC + bh * Tt + c * Ss + tid];
        float bt = ig[bh * Tt + c * Ss + tid] - lfa;
        sbt[tid] = bt;
        snp[tid] = nprev[tid];
        pm = bt;
        for (int off = 1; off < 64; off <<= 1) {
            float o = __shfl_up(pm, off);
            if (lane64 >= off) pm = fmaxf(pm, o);
        }
        if (lane64 == 63) scomb[wv] = pm;
    }
    __syncthreads();   // barrier A: Xb(K) staged, sbt/snp/scomb ready

    // ---- phase 0 part 2 (p0) + intern raw dot (all waves) ----
    if (p0) {
        if (wv == 1) pm = fmaxf(pm, scomb[0]);
        float mx = fmaxf(pm, m_prev);
        sas[tid] = -mx;
        siw[tid] = SCALE * __expf(m_prev - mx);
        sengs[tid] = __expf(-(lfa + mx));
    }
    {
        float d = 0.f;
#pragma unroll
        for (int kk = 0; kk < 4; kk++)
#pragma unroll
            for (int e = 0; e < 8; e++)
                d += (float)qf[kk][e] * snp[kk * 32 + g * 8 + e];
        d += __shfl_xor(d, 16);
        d += __shfl_xor(d, 32);
        if (g == 0) sintern[S0 + l15] = d;   // raw q.n_prev (iw applied later)
    }
    __syncthreads();   // barrier B: sas/siw/sengs ready

    // ---- per-lane row constants ----
    float asr[4], siwr[4];
#pragma unroll
    for (int r = 0; r < 4; r++) {
        int sr = S0 + 4 * g + r;
        asr[r] = sas[sr];
        siwr[r] = siw[sr];
    }

    // ---- QK^T + gating -> Mb (own rows) + row sums ----
    float rp[4] = {0.f, 0.f, 0.f, 0.f};
    for (int tj = 0; tj <= w; tj++) {
        int trow = tj * 16 + l15;
        f16x8 bfr[4];
#pragma unroll
        for (int kk = 0; kk < 4; kk++)
            bfr[kk] = *(const f16x8*)&Xb[trow * Kk + ((kk * 32 + g * 8) ^ swt)];
        float btv = sbt[trow];
        f32x4 acc = {0.f, 0.f, 0.f, 0.f};
#pragma unroll
        for (int kk = 0; kk < 4; kk++)
            acc = __builtin_amdgcn_mfma_f32_16x16x32_f16(qf[kk], bfr[kk], acc, 0, 0, 0);
#pragma unroll
        for (int r = 0; r < 4; r++) {
            int sr = S0 + 4 * g + r;
            float val = 0.f;
            if (trow <= sr) {
                val = acc[r] * SCALE * __expf(asr[r] + btv);
                rp[r] += val;
            }
            Mb[sr * Ss + (trow ^ ((sr & 7) << 3))] = (_Float16)val;
        }
    }
    // even-w waves: zero the 16-col strip PV's top fragment overreads
    if (!(w & 1)) {
        int row = S0 + l15;
        int c0 = S0 + 16 + 4 * g;
        *(f16x4*)&Mb[row * Ss + (c0 ^ ((l15 & 7) << 3))] = (f16x4){(_Float16)0.f, (_Float16)0.f, (_Float16)0.f, (_Float16)0.f};
    }
    // row-sum reduce across t-residues
#pragma unroll
    for (int r = 0; r < 4; r++) {
        float t = rp[r];
        t += __shfl_xor(t, 1);
        t += __shfl_xor(t, 2);
        t += __shfl_xor(t, 4);
        t += __shfl_xor(t, 8);
        if (l15 == 0) srow[S0 + 4 * g + r] = t;
    }
    __syncthreads();   // barrier C: Mb+srow+sintern complete; Xb(K) free

    // ---- M_norm (p0); stage V^T into Xb (4x4 register transpose) ----
    if (p0) smn[tid] = fmaxf(fabsf(srow[tid] + sintern[tid] * siw[tid]), sengs[tid]);
#pragma unroll
    for (int rep = 0; rep < 2; rep++) {
        int tau = tid + rep * 512;
        int v0 = (tau & 31) * 4;
        int t0 = (tau >> 5) * 4;
        const float* vsrc = vp + (size_t)t0 * Vv + v0;
        float4 a0 = *(const float4*)(vsrc);
        float4 a1 = *(const float4*)(vsrc + Vv);
        float4 a2 = *(const float4*)(vsrc + 2 * Vv);
        float4 a3 = *(const float4*)(vsrc + 3 * Vv);
#pragma unroll
        for (int jc = 0; jc < 4; jc++) {
            float e0 = (jc == 0 ? a0.x : jc == 1 ? a0.y : jc == 2 ? a0.z : a0.w);
            float e1 = (jc == 0 ? a1.x : jc == 1 ? a1.y : jc == 2 ? a1.z : a1.w);
            float e2 = (jc == 0 ? a2.x : jc == 1 ? a2.y : jc == 2 ? a2.z : a2.w);
            float e3 = (jc == 0 ? a3.x : jc == 1 ? a3.y : jc == 2 ? a3.z : a3.w);
            int row = v0 + jc;
            int col = t0 ^ ((row & 7) << 3);
            f16x4 s4 = { (_Float16)e0, (_Float16)e1, (_Float16)e2, (_Float16)e3 };
            *(f16x4*)&Xb[row * Ss + col] = s4;
        }
    }
    __syncthreads();   // barrier D: V^T staged, smn ready

    // ---- PV (own Mb rows) + inter (c_prev^T direct from HBM) ----
    f32x4 hacc[8];
#pragma unroll
    for (int vj = 0; vj < 8; vj++) hacc[vj] = (f32x4){0.f, 0.f, 0.f, 0.f};

    for (int kkt = 0; kkt <= (w >> 1); kkt++) {
        f16x8 af = *(const f16x8*)&Mb[(S0 + l15) * Ss + ((kkt * 32 + g * 8) ^ swt)];
#pragma unroll
        for (int vj = 0; vj < 8; vj++) {
            int vr = vj * 16 + l15;
            f16x8 bv = *(const f16x8*)&Xb[vr * Ss + ((kkt * 32 + g * 8) ^ swt)];
            hacc[vj] = __builtin_amdgcn_mfma_f32_16x16x32_f16(af, bv, hacc[vj], 0, 0, 0);
        }
    }

    for (int vj = 0; vj < 8; vj++) {
        f32x4 tmp = {0.f, 0.f, 0.f, 0.f};
        const _Float16* cpr = cprevT + (size_t)(vj * 16 + l15) * Kk + g * 8;
#pragma unroll
        for (int kk = 0; kk < 4; kk++) {
            f16x8 bcf = *(const f16x8*)(cpr + kk * 32);
            tmp = __builtin_amdgcn_mfma_f32_16x16x32_f16(qf[kk], bcf, tmp, 0, 0, 0);
        }
#pragma unroll
        for (int r = 0; r < 4; r++)
            hacc[vj][r] += tmp[r] * siwr[r];
    }

    // ---- output: h = hacc / M_norm ----
    float rnv[4];
#pragma unroll
    for (int r = 0; r < 4; r++) rnv[r] = 1.0f / smn[S0 + 4 * g + r];

#pragma unroll
    for (int vj = 0; vj < 8; vj++)
#pragma unroll
        for (int r = 0; r < 4; r++) {
            int sr = S0 + 4 * g + r;
            out[(rowbase + sr) * Vv + vj * 16 + l15] = hacc[vj][r] * rnv[r];
        }
}

// ---------------------------------------------------------------------------
extern "C" void kernel_launch(void* const* d_in, const int* in_sizes, int n_in,
                              void* d_out, int out_size, void* d_ws, size_t ws_size,
                              hipStream_t stream) {
    (void)in_sizes; (void)n_in; (void)out_size; (void)ws_size;
    const float* q  = (const float*)d_in[0];
    const float* k  = (const float*)d_in[1];
    const float* v  = (const float*)d_in[2];
    const float* ig = (const float*)d_in[3];
    const float* fg = (const float*)d_in[4];
    const float* C0 = (const float*)d_in[5];
    const float* n0 = (const float*)d_in[6];
    const float* m0 = (const float*)d_in[7];
    float* out = (float*)d_out;
    float* ws  = (float*)d_ws;

    k_kvg<<<BH * Cc, 512, 0, stream>>>(ig, fg, k, v, ws);
    k_scan_coef<<<1, 64, 0, stream>>>(m0, ws);
    k_scan_apply<<<(BH * Kk * Vv / 2 + BH * Kk) / 256, 256, 0, stream>>>(C0, n0, ws);
    k_out_mfma<<<BH * Cc, 512, 0, stream>>>(q, k, v, ig, ws, out);
}